// Round 2
// baseline (1006.654 us; speedup 1.0000x reference)
//
#include <hip/hip_runtime.h>
#include <hip/hip_bf16.h>

#define BB 32
#define TT 3136
#define DD 147
#define EE 64
#define MM 32
#define BT (BB*TT)      // 100352
#define SEG 28
#define TSEG (TT/SEG)   // 112

typedef __hip_bfloat16 bf16;

__device__ __forceinline__ float b2f(bf16 v){ return __bfloat162float(v); }
__device__ __forceinline__ bf16 f2b(float v){ return __float2bfloat16(v); }

template<typename T>
__device__ __forceinline__ float cvt1(T v);
template<> __device__ __forceinline__ float cvt1<float>(float v){ return v; }
template<> __device__ __forceinline__ float cvt1<bf16>(bf16 v){ return __bfloat162float(v); }

// ---------------- detect: inputs bf16 (flag=1) or fp32 (flag=0) ------------
__global__ void k_detect(const unsigned* __restrict__ g1u, int* __restrict__ flagp){
  if (threadIdx.x == 0 && blockIdx.x == 0)
    *flagp = (g1u[0] == 0x3F803F80u) ? 1 : 0;
}

// ---------------- cvt: all weights -> canonical fp32 in ws -----------------
template<typename T>
__device__ void cvt_body(int idx,
    const T* wkqv, const T* bkqv, const T* Wrf, const T* wproj, const T* bproj,
    const T* g2, const T* be2, const T* wm1, const T* bm1, const T* wm2,
    const T* bm2, const T* g1, const T* be1,
    float* wT, float* bkqvF, float* WrfF, float* wprojF, float* bprojF,
    float* g2F, float* be2F, float* wm1F, float* bm1F, float* wm2F,
    float* bm2F, float* g1F, float* be1F)
{
  if (idx < 28224){ int c = idx/DD, d = idx - c*DD; wT[d*192+c] = cvt1(wkqv[idx]); return; }
  idx -= 28224;
  if (idx < 192){ bkqvF[idx] = cvt1(bkqv[idx]); return; }
  idx -= 192;
  if (idx < 2048){ WrfF[idx] = cvt1(Wrf[idx]); return; }
  idx -= 2048;
  if (idx < 4096){ wprojF[idx] = cvt1(wproj[idx]); return; }
  idx -= 4096;
  if (idx < 64){ bprojF[idx] = cvt1(bproj[idx]); return; }
  idx -= 64;
  if (idx < 64){ g2F[idx] = cvt1(g2[idx]); return; }
  idx -= 64;
  if (idx < 64){ be2F[idx] = cvt1(be2[idx]); return; }
  idx -= 64;
  if (idx < 4096){ wm1F[idx] = cvt1(wm1[idx]); return; }
  idx -= 4096;
  if (idx < 64){ bm1F[idx] = cvt1(bm1[idx]); return; }
  idx -= 64;
  if (idx < 4096){ wm2F[idx] = cvt1(wm2[idx]); return; }
  idx -= 4096;
  if (idx < 64){ bm2F[idx] = cvt1(bm2[idx]); return; }
  idx -= 64;
  if (idx < DD){ g1F[idx] = cvt1(g1[idx]); return; }
  idx -= DD;
  if (idx < DD){ be1F[idx] = cvt1(be1[idx]); return; }
}

__global__ void k_cvt(const void* wkqv, const void* bkqv, const void* Wrf,
    const void* wproj, const void* bproj, const void* g2, const void* be2,
    const void* wm1, const void* bm1, const void* wm2, const void* bm2,
    const void* g1, const void* be1, const int* __restrict__ flagp,
    float* wT, float* bkqvF, float* WrfF, float* wprojF, float* bprojF,
    float* g2F, float* be2F, float* wm1F, float* bm1F, float* wm2F,
    float* bm2F, float* g1F, float* be1F)
{
  int idx = blockIdx.x*256 + threadIdx.x;
  if (*flagp)
    cvt_body<bf16>(idx, (const bf16*)wkqv, (const bf16*)bkqv, (const bf16*)Wrf,
      (const bf16*)wproj, (const bf16*)bproj, (const bf16*)g2, (const bf16*)be2,
      (const bf16*)wm1, (const bf16*)bm1, (const bf16*)wm2, (const bf16*)bm2,
      (const bf16*)g1, (const bf16*)be1,
      wT, bkqvF, WrfF, wprojF, bprojF, g2F, be2F, wm1F, bm1F, wm2F, bm2F, g1F, be1F);
  else
    cvt_body<float>(idx, (const float*)wkqv, (const float*)bkqv, (const float*)Wrf,
      (const float*)wproj, (const float*)bproj, (const float*)g2, (const float*)be2,
      (const float*)wm1, (const float*)bm1, (const float*)wm2, (const float*)bm2,
      (const float*)g1, (const float*)be1,
      wT, bkqvF, WrfF, wprojF, bprojF, g2F, be2F, wm1F, bm1F, wm2F, bm2F, g1F, be1F);
}

// ---------------- LN1: wave per token --------------------------------------
template<typename T>
__device__ void ln1_body(const T* __restrict__ x, const float* __restrict__ g1F,
                         const float* __restrict__ be1F, bf16* __restrict__ xn){
  int lane = threadIdx.x & 63;
  int t = blockIdx.x*4 + (threadIdx.x>>6);
  int base = t*DD;
  float v0 = cvt1(x[base+lane]);
  float v1 = cvt1(x[base+64+lane]);
  float v2 = (lane < DD-128) ? cvt1(x[base+128+lane]) : 0.f;
  float s = v0+v1+v2, s2 = v0*v0+v1*v1+v2*v2;
  #pragma unroll
  for (int off=32; off; off>>=1){ s += __shfl_xor(s,off); s2 += __shfl_xor(s2,off); }
  float mu  = s * (1.f/147.f);
  float var = s2 * (1.f/147.f) - mu*mu;
  float r = rsqrtf(var + 1e-5f);
  bf16* xo = xn + base;
  xo[lane]    = f2b((v0-mu)*r*g1F[lane]    + be1F[lane]);
  xo[64+lane] = f2b((v1-mu)*r*g1F[64+lane] + be1F[64+lane]);
  if (lane < DD-128)
    xo[128+lane] = f2b((v2-mu)*r*g1F[128+lane] + be1F[128+lane]);
}

__global__ void k_ln1(const void* __restrict__ x, const float* __restrict__ g1F,
                      const float* __restrict__ be1F, const int* __restrict__ flagp,
                      bf16* __restrict__ xn){
  if (*flagp) ln1_body<bf16>((const bf16*)x, g1F, be1F, xn);
  else        ln1_body<float>((const float*)x, g1F, be1F, xn);
}

// ---------------- A2: kqv GEMM + prm_exp epilogue --------------------------
// block: 256 threads, tile 64 tokens x 192 channels, thread tile 4x12
__global__ __launch_bounds__(256,2) void k_a2(
    const bf16* __restrict__ xn, const float* __restrict__ wT,
    const float* __restrict__ bkqvF, const float* __restrict__ WrfF,
    float* __restrict__ kp, float* __restrict__ qp, bf16* __restrict__ v)
{
  __shared__ float uS[12672];      // phase1: aS[64][51] + bS[49][192]; phase2: kqvS[64][193]
  __shared__ float WrfS[32*65];
  __shared__ float xdS[128];
  float* aS = uS;
  float* bS = uS + 64*51;
  float* kqvS = uS;

  int tid = threadIdx.x;
  int t0 = blockIdx.x*64;
  for (int idx = tid; idx < 32*64; idx += 256){
    int m = idx>>6, e = idx&63;
    WrfS[m*65+e] = WrfF[idx];
  }
  int tr = tid>>4, tc = tid&15;
  int tr4 = tr*4, tc12 = tc*12;
  float bias[12];
  #pragma unroll
  for (int j=0;j<12;j++) bias[j] = bkqvF[tc12+j];
  float acc[4][12];
  #pragma unroll
  for (int i=0;i<4;i++)
    #pragma unroll
    for (int j=0;j<12;j++) acc[i][j]=0.f;

  for (int ch=0; ch<3; ++ch){
    __syncthreads();
    for (int idx = tid; idx < 64*49; idx += 256){
      int tk = idx/49, d = idx - tk*49;
      aS[tk*51+d] = b2f(xn[(t0+tk)*DD + ch*49 + d]);
    }
    const float* wsrc = wT + ch*49*192;
    for (int idx = tid; idx < 49*192; idx += 256) bS[idx] = wsrc[idx];
    __syncthreads();
    for (int d=0; d<49; ++d){
      float av[4], bv[12];
      #pragma unroll
      for (int i=0;i<4;i++) av[i] = aS[(tr4+i)*51 + d];
      #pragma unroll
      for (int j=0;j<12;j++) bv[j] = bS[d*192 + tc12 + j];
      #pragma unroll
      for (int i=0;i<4;i++)
        #pragma unroll
        for (int j=0;j<12;j++) acc[i][j] = fmaf(av[i], bv[j], acc[i][j]);
    }
  }
  __syncthreads();
  #pragma unroll
  for (int i=0;i<4;i++)
    #pragma unroll
    for (int j=0;j<12;j++)
      kqvS[(tr4+i)*193 + tc12 + j] = acc[i][j] + bias[j];
  __syncthreads();
  // v out (channels 128..191), bf16
  for (int idx = tid; idx < 64*64; idx += 256){
    int tk = idx>>6, e = idx&63;
    v[(t0+tk)*64 + e] = f2b(kqvS[tk*193 + 128 + e]);
  }
  // xd = 0.5*||k||^2 / 0.5*||q||^2
  if (tid < 128){
    int which = tid>>6, tk = tid&63;
    const float* row = &kqvS[tk*193 + which*64];
    float s = 0.f;
    #pragma unroll
    for (int e=0;e<64;e++){ float z = row[e]; s = fmaf(z,z,s); }
    xdS[which*64+tk] = 0.5f*s;
  }
  __syncthreads();
  // kp/qp = exp(wtx - xd)/sqrt(32)
  for (int kk=0; kk<16; ++kk){
    int idx = tid + 256*kk;
    int which = idx>>11;
    int rem = idx & 2047;
    int tk = rem>>5, m = rem&31;
    const float* row = &kqvS[tk*193 + which*64];
    const float* wr  = &WrfS[m*65];
    float s = 0.f;
    #pragma unroll
    for (int e=0;e<64;e++) s = fmaf(row[e], wr[e], s);
    float val = expf(s - xdS[which*64+tk]) * 0.17677669529663687f;
    float* dst = which ? qp : kp;
    dst[(t0+tk)*32 + m] = val;
  }
}

// ---------------- R1: partial kptv/ksum over 112-token segments ------------
__global__ void k_red(const bf16* __restrict__ v, const float* __restrict__ kp,
                      float* __restrict__ kptvP, float* __restrict__ ksumP){
  __shared__ float vS[16*64];
  __shared__ float kpS[16*32];
  int tid = threadIdx.x;
  int s = blockIdx.x, b = blockIdx.y;
  int tbase = b*TT + s*TSEG;
  float acc[8];
  #pragma unroll
  for (int p=0;p<8;p++) acc[p]=0.f;
  float ks = 0.f;
  int m  = tid & 31;
  int e0 = tid >> 5;
  for (int c=0;c<7;c++){
    __syncthreads();
    for (int idx=tid; idx<1024; idx+=256)
      vS[idx] = b2f(v[(tbase + c*16 + (idx>>6))*64 + (idx&63)]);
    for (int idx=tid; idx<512; idx+=256)
      kpS[idx] = kp[(tbase + c*16 + (idx>>5))*32 + (idx&31)];
    __syncthreads();
    #pragma unroll 4
    for (int t=0;t<16;t++){
      float kv = kpS[t*32 + m];
      #pragma unroll
      for (int p=0;p<8;p++)
        acc[p] = fmaf(vS[t*64 + e0 + 8*p], kv, acc[p]);
      if (tid < 32) ks += kpS[t*32 + tid];
    }
  }
  int ob = (b*SEG + s);
  #pragma unroll
  for (int p=0;p<8;p++) kptvP[ob*2048 + tid + 256*p] = acc[p];
  if (tid<32) ksumP[ob*32 + tid] = ks;
}

// ---------------- R2: final reduce ----------------------------------------
__global__ void k_red2(const float* __restrict__ kptvP, const float* __restrict__ ksumP,
                       float* __restrict__ kptvF, float* __restrict__ ksumF){
  int b = blockIdx.x, tid = threadIdx.x;
  #pragma unroll
  for (int p=0;p<8;p++){
    int idx = tid + 256*p;
    float s = 0.f;
    for (int g=0; g<SEG; ++g) s += kptvP[(b*SEG+g)*2048 + idx];
    kptvF[b*2048+idx] = s;
  }
  if (tid<32){
    float s=0.f;
    for (int g=0; g<SEG; ++g) s += ksumP[(b*SEG+g)*32 + tid];
    ksumF[b*32+tid]=s;
  }
}

// ---------------- B: attn-out + proj + LN2 + MLP, wave per token -----------
__global__ __launch_bounds__(256,2) void k_b(
    const float* __restrict__ qp, const bf16* __restrict__ v,
    const float* __restrict__ kptvF, const float* __restrict__ ksumF,
    const float* __restrict__ wprojF, const float* __restrict__ bprojF,
    const float* __restrict__ g2F, const float* __restrict__ be2F,
    const float* __restrict__ wm1F, const float* __restrict__ bm1F,
    const float* __restrict__ wm2F, const float* __restrict__ bm2F,
    const int* __restrict__ flagp, void* __restrict__ outp)
{
  __shared__ float wpS[64*65], wm1S[64*65], wm2S[64*65];
  __shared__ float kvS[64*33];
  __shared__ float ksS[32];
  __shared__ float bpS[64], b1S[64], b2S[64], gS[64], btS[64];
  int flag = *flagp;
  int tid = threadIdx.x;
  int b = blockIdx.y, t0 = blockIdx.x*32;
  for (int idx=tid; idx<4096; idx+=256){
    int e = idx>>6, j = idx&63;
    wpS[e*65+j]  = wprojF[idx];
    wm1S[e*65+j] = wm1F[idx];
    wm2S[e*65+j] = wm2F[idx];
  }
  for (int idx=tid; idx<2048; idx+=256)
    kvS[(idx>>5)*33 + (idx&31)] = kptvF[b*2048 + idx];
  if (tid<32) ksS[tid] = ksumF[b*32+tid];
  if (tid<64){
    bpS[tid]=bprojF[tid]; b1S[tid]=bm1F[tid]; b2S[tid]=bm2F[tid];
    gS[tid]=g2F[tid]; btS[tid]=be2F[tid];
  }
  __syncthreads();
  int wv = tid>>6, lane = tid&63;
  #pragma unroll 1
  for (int it=0; it<8; ++it){
    int t = t0 + wv*8 + it;
    int gt = b*TT + t;
    float qpv = (lane<32) ? qp[gt*32+lane] : 0.f;
    float Dp  = (lane<32) ? qpv*ksS[lane] : 0.f;
    #pragma unroll
    for (int off=32; off; off>>=1) Dp += __shfl_xor(Dp, off);
    float rD = 1.f/(Dp + 1e-8f);
    float acc = 0.f;
    #pragma unroll
    for (int m=0;m<32;m++) acc = fmaf(__shfl(qpv, m), kvS[lane*33+m], acc);
    float ya = acc * rD;
    float ve = b2f(v[gt*64+lane]);
    float s = 0.f;
    #pragma unroll
    for (int j=0;j<64;j++) s = fmaf(__shfl(ya, j), wpS[lane*65+j], s);
    float y = ve + s + bpS[lane];
    // LN2
    float ssum = y;
    #pragma unroll
    for (int off=32; off; off>>=1) ssum += __shfl_xor(ssum, off);
    float mu = ssum * (1.f/64.f);
    float dd = y - mu;
    float vsum = dd*dd;
    #pragma unroll
    for (int off=32; off; off>>=1) vsum += __shfl_xor(vsum, off);
    float r = rsqrtf(vsum*(1.f/64.f) + 1e-5f);
    float yn = dd*r*gS[lane] + btS[lane];
    // MLP
    float h = b1S[lane];
    #pragma unroll
    for (int j=0;j<64;j++) h = fmaf(__shfl(yn, j), wm1S[lane*65+j], h);
    h = 0.5f*h*(1.f + erff(h*0.70710678118654752f));
    float o = y + b2S[lane];
    #pragma unroll
    for (int j=0;j<64;j++) o = fmaf(__shfl(h, j), wm2S[lane*65+j], o);
    if (flag) ((bf16*)outp)[gt*64+lane] = f2b(o);
    else      ((float*)outp)[gt*64+lane] = o;
  }
}

// ---------------- launcher -------------------------------------------------
extern "C" void kernel_launch(void* const* d_in, const int* in_sizes, int n_in,
                              void* d_out, int out_size, void* d_ws, size_t ws_size,
                              hipStream_t stream){
  const void* x    = d_in[0];
  const void* wkqv = d_in[1];
  const void* bkqv = d_in[2];
  const void* wproj= d_in[3];
  const void* bproj= d_in[4];
  const void* g1   = d_in[5];
  const void* be1  = d_in[6];
  const void* g2   = d_in[7];
  const void* be2  = d_in[8];
  const void* wm1  = d_in[9];
  const void* bm1  = d_in[10];
  const void* wm2  = d_in[11];
  const void* bm2  = d_in[12];
  const void* Wrf  = d_in[13];

  char* ws = (char*)d_ws;
  int*   flagp = (int*)(ws + 0);
  float* wT    = (float*)(ws + 256);
  float* bkqvF = (float*)(ws + 113152);
  float* WrfF  = (float*)(ws + 113920);
  float* wprojF= (float*)(ws + 122112);
  float* bprojF= (float*)(ws + 138496);
  float* g2F   = (float*)(ws + 138752);
  float* be2F  = (float*)(ws + 139008);
  float* wm1F  = (float*)(ws + 139264);
  float* bm1F  = (float*)(ws + 155648);
  float* wm2F  = (float*)(ws + 155904);
  float* bm2F  = (float*)(ws + 172288);
  float* g1F   = (float*)(ws + 172544);
  float* be1F  = (float*)(ws + 173184);
  bf16*  xn    = (bf16*) (ws + 174080);
  float* kp    = (float*)(ws + 29677568);
  float* qp    = (float*)(ws + 42522624);
  bf16*  v     = (bf16*) (ws + 55367680);
  float* kptvP = (float*)(ws + 68212736);
  float* ksumP = (float*)(ws + 75552768);
  float* kptvF = (float*)(ws + 75667456);
  float* ksumF = (float*)(ws + 75929600);

  k_detect<<<1, 64, 0, stream>>>((const unsigned*)g1, flagp);
  k_cvt<<<170, 256, 0, stream>>>(wkqv, bkqv, Wrf, wproj, bproj, g2, be2,
      wm1, bm1, wm2, bm2, g1, be1, flagp,
      wT, bkqvF, WrfF, wprojF, bprojF, g2F, be2F, wm1F, bm1F, wm2F, bm2F, g1F, be1F);
  k_ln1<<<BT/4, 256, 0, stream>>>(x, g1F, be1F, flagp, xn);
  k_a2<<<BT/64, 256, 0, stream>>>(xn, wT, bkqvF, WrfF, kp, qp, v);
  k_red<<<dim3(SEG, BB), 256, 0, stream>>>(v, kp, kptvP, ksumP);
  k_red2<<<BB, 256, 0, stream>>>(kptvP, ksumP, kptvF, ksumF);
  k_b<<<dim3(TT/32, BB), 256, 0, stream>>>(qp, v, kptvF, ksumF,
      wprojF, bprojF, g2F, be2F, wm1F, bm1F, wm2F, bm2F, flagp, d_out);
}

// Round 4
// 422.187 us; speedup vs baseline: 2.3844x; 2.3844x over previous
//
#include <hip/hip_runtime.h>
#include <hip/hip_bf16.h>

#define BB 32
#define TT 3136
#define DD 147
#define EE 64
#define MM 32
#define BT (BB*TT)      // 100352
#define SEG 28
#define TSEG (TT/SEG)   // 112

typedef __hip_bfloat16 bf16;
typedef __attribute__((ext_vector_type(8))) short s8v;
typedef __attribute__((ext_vector_type(4))) float f4v;

__device__ __forceinline__ float b2f(bf16 v){ return __bfloat162float(v); }
__device__ __forceinline__ bf16 f2b(float v){ return __float2bfloat16(v); }

template<typename T>
__device__ __forceinline__ float cvt1(T v);
template<> __device__ __forceinline__ float cvt1<float>(float v){ return v; }
template<> __device__ __forceinline__ float cvt1<bf16>(bf16 v){ return __bfloat162float(v); }

// ---------------- detect: inputs bf16 (flag=1) or fp32 (flag=0) ------------
__global__ void k_detect(const unsigned* __restrict__ g1u, int* __restrict__ flagp){
  if (threadIdx.x == 0 && blockIdx.x == 0)
    *flagp = (g1u[0] == 0x3F803F80u) ? 1 : 0;
}

// ---------------- cvt: all weights -> canonical fp32 in ws -----------------
template<typename T>
__device__ void cvt_body(int idx,
    const T* wkqv, const T* bkqv, const T* Wrf, const T* wproj, const T* bproj,
    const T* g2, const T* be2, const T* wm1, const T* bm1, const T* wm2,
    const T* bm2, const T* g1, const T* be1,
    float* wT, float* bkqvF, float* WrfF, float* wprojF, float* bprojF,
    float* g2F, float* be2F, float* wm1F, float* bm1F, float* wm2F,
    float* bm2F, float* g1F, float* be1F)
{
  if (idx < 28224){ int c = idx/DD, d = idx - c*DD; wT[d*192+c] = cvt1(wkqv[idx]); return; }
  idx -= 28224;
  if (idx < 192){ bkqvF[idx] = cvt1(bkqv[idx]); return; }
  idx -= 192;
  if (idx < 2048){ WrfF[idx] = cvt1(Wrf[idx]); return; }
  idx -= 2048;
  if (idx < 4096){ wprojF[idx] = cvt1(wproj[idx]); return; }
  idx -= 4096;
  if (idx < 64){ bprojF[idx] = cvt1(bproj[idx]); return; }
  idx -= 64;
  if (idx < 64){ g2F[idx] = cvt1(g2[idx]); return; }
  idx -= 64;
  if (idx < 64){ be2F[idx] = cvt1(be2[idx]); return; }
  idx -= 64;
  if (idx < 4096){ wm1F[idx] = cvt1(wm1[idx]); return; }
  idx -= 4096;
  if (idx < 64){ bm1F[idx] = cvt1(bm1[idx]); return; }
  idx -= 64;
  if (idx < 4096){ wm2F[idx] = cvt1(wm2[idx]); return; }
  idx -= 4096;
  if (idx < 64){ bm2F[idx] = cvt1(bm2[idx]); return; }
  idx -= 64;
  if (idx < DD){ g1F[idx] = cvt1(g1[idx]); return; }
  idx -= DD;
  if (idx < DD){ be1F[idx] = cvt1(be1[idx]); return; }
}

__global__ void k_cvt(const void* wkqv, const void* bkqv, const void* Wrf,
    const void* wproj, const void* bproj, const void* g2, const void* be2,
    const void* wm1, const void* bm1, const void* wm2, const void* bm2,
    const void* g1, const void* be1, const int* __restrict__ flagp,
    float* wT, float* bkqvF, float* WrfF, float* wprojF, float* bprojF,
    float* g2F, float* be2F, float* wm1F, float* bm1F, float* wm2F,
    float* bm2F, float* g1F, float* be1F)
{
  int idx = blockIdx.x*256 + threadIdx.x;
  if (*flagp)
    cvt_body<bf16>(idx, (const bf16*)wkqv, (const bf16*)bkqv, (const bf16*)Wrf,
      (const bf16*)wproj, (const bf16*)bproj, (const bf16*)g2, (const bf16*)be2,
      (const bf16*)wm1, (const bf16*)bm1, (const bf16*)wm2, (const bf16*)bm2,
      (const bf16*)g1, (const bf16*)be1,
      wT, bkqvF, WrfF, wprojF, bprojF, g2F, be2F, wm1F, bm1F, wm2F, bm2F, g1F, be1F);
  else
    cvt_body<float>(idx, (const float*)wkqv, (const float*)bkqv, (const float*)Wrf,
      (const float*)wproj, (const float*)bproj, (const float*)g2, (const float*)be2,
      (const float*)wm1, (const float*)bm1, (const float*)wm2, (const float*)bm2,
      (const float*)g1, (const float*)be1,
      wT, bkqvF, WrfF, wprojF, bprojF, g2F, be2F, wm1F, bm1F, wm2F, bm2F, g1F, be1F);
}

// ---------------- LN1: wave per token --------------------------------------
template<typename T>
__device__ void ln1_body(const T* __restrict__ x, const float* __restrict__ g1F,
                         const float* __restrict__ be1F, bf16* __restrict__ xn){
  int lane = threadIdx.x & 63;
  int t = blockIdx.x*4 + (threadIdx.x>>6);
  int base = t*DD;
  float v0 = cvt1(x[base+lane]);
  float v1 = cvt1(x[base+64+lane]);
  float v2 = (lane < DD-128) ? cvt1(x[base+128+lane]) : 0.f;
  float s = v0+v1+v2, s2 = v0*v0+v1*v1+v2*v2;
  #pragma unroll
  for (int off=32; off; off>>=1){ s += __shfl_xor(s,off); s2 += __shfl_xor(s2,off); }
  float mu  = s * (1.f/147.f);
  float var = s2 * (1.f/147.f) - mu*mu;
  float r = rsqrtf(var + 1e-5f);
  bf16* xo = xn + base;
  xo[lane]    = f2b((v0-mu)*r*g1F[lane]    + be1F[lane]);
  xo[64+lane] = f2b((v1-mu)*r*g1F[64+lane] + be1F[64+lane]);
  if (lane < DD-128)
    xo[128+lane] = f2b((v2-mu)*r*g1F[128+lane] + be1F[128+lane]);
}

__global__ void k_ln1(const void* __restrict__ x, const float* __restrict__ g1F,
                      const float* __restrict__ be1F, const int* __restrict__ flagp,
                      bf16* __restrict__ xn){
  if (*flagp) ln1_body<bf16>((const bf16*)x, g1F, be1F, xn);
  else        ln1_body<float>((const float*)x, g1F, be1F, xn);
}

// ---------------- A2: kqv GEMM + prm_exp epilogue --------------------------
__global__ __launch_bounds__(256,2) void k_a2(
    const bf16* __restrict__ xn, const float* __restrict__ wT,
    const float* __restrict__ bkqvF, const float* __restrict__ WrfF,
    float* __restrict__ kp, float* __restrict__ qp, bf16* __restrict__ v)
{
  __shared__ float uS[12672];      // phase1: aS[64][51] + bS[49][192]; phase2: kqvS[64][193]
  __shared__ float WrfS[32*65];
  __shared__ float xdS[128];
  float* aS = uS;
  float* bS = uS + 64*51;
  float* kqvS = uS;

  int tid = threadIdx.x;
  int t0 = blockIdx.x*64;
  for (int idx = tid; idx < 32*64; idx += 256){
    int m = idx>>6, e = idx&63;
    WrfS[m*65+e] = WrfF[idx];
  }
  int tr = tid>>4, tc = tid&15;
  int tr4 = tr*4, tc12 = tc*12;
  float bias[12];
  #pragma unroll
  for (int j=0;j<12;j++) bias[j] = bkqvF[tc12+j];
  float acc[4][12];
  #pragma unroll
  for (int i=0;i<4;i++)
    #pragma unroll
    for (int j=0;j<12;j++) acc[i][j]=0.f;

  for (int ch=0; ch<3; ++ch){
    __syncthreads();
    for (int idx = tid; idx < 64*49; idx += 256){
      int tk = idx/49, d = idx - tk*49;
      aS[tk*51+d] = b2f(xn[(t0+tk)*DD + ch*49 + d]);
    }
    const float* wsrc = wT + ch*49*192;
    for (int idx = tid; idx < 49*192; idx += 256) bS[idx] = wsrc[idx];
    __syncthreads();
    for (int d=0; d<49; ++d){
      float av[4], bv[12];
      #pragma unroll
      for (int i=0;i<4;i++) av[i] = aS[(tr4+i)*51 + d];
      #pragma unroll
      for (int j=0;j<12;j++) bv[j] = bS[d*192 + tc12 + j];
      #pragma unroll
      for (int i=0;i<4;i++)
        #pragma unroll
        for (int j=0;j<12;j++) acc[i][j] = fmaf(av[i], bv[j], acc[i][j]);
    }
  }
  __syncthreads();
  #pragma unroll
  for (int i=0;i<4;i++)
    #pragma unroll
    for (int j=0;j<12;j++)
      kqvS[(tr4+i)*193 + tc12 + j] = acc[i][j] + bias[j];
  __syncthreads();
  for (int idx = tid; idx < 64*64; idx += 256){
    int tk = idx>>6, e = idx&63;
    v[(t0+tk)*64 + e] = f2b(kqvS[tk*193 + 128 + e]);
  }
  if (tid < 128){
    int which = tid>>6, tk = tid&63;
    const float* row = &kqvS[tk*193 + which*64];
    float s = 0.f;
    #pragma unroll
    for (int e=0;e<64;e++){ float z = row[e]; s = fmaf(z,z,s); }
    xdS[which*64+tk] = 0.5f*s;
  }
  __syncthreads();
  for (int kk=0; kk<16; ++kk){
    int idx = tid + 256*kk;
    int which = idx>>11;
    int rem = idx & 2047;
    int tk = rem>>5, m = rem&31;
    const float* row = &kqvS[tk*193 + which*64];
    const float* wr  = &WrfS[m*65];
    float s = 0.f;
    #pragma unroll
    for (int e=0;e<64;e++) s = fmaf(row[e], wr[e], s);
    float val = expf(s - xdS[which*64+tk]) * 0.17677669529663687f;
    float* dst = which ? qp : kp;
    dst[(t0+tk)*32 + m] = val;
  }
}

// ---------------- R1: partial kptv/ksum over 112-token segments ------------
__global__ void k_red(const bf16* __restrict__ v, const float* __restrict__ kp,
                      float* __restrict__ kptvP, float* __restrict__ ksumP){
  __shared__ float vS[16*64];
  __shared__ float kpS[16*32];
  int tid = threadIdx.x;
  int s = blockIdx.x, b = blockIdx.y;
  int tbase = b*TT + s*TSEG;
  float acc[8];
  #pragma unroll
  for (int p=0;p<8;p++) acc[p]=0.f;
  float ks = 0.f;
  int m  = tid & 31;
  int e0 = tid >> 5;
  for (int c=0;c<7;c++){
    __syncthreads();
    for (int idx=tid; idx<1024; idx+=256)
      vS[idx] = b2f(v[(tbase + c*16 + (idx>>6))*64 + (idx&63)]);
    for (int idx=tid; idx<512; idx+=256)
      kpS[idx] = kp[(tbase + c*16 + (idx>>5))*32 + (idx&31)];
    __syncthreads();
    #pragma unroll 4
    for (int t=0;t<16;t++){
      float kv = kpS[t*32 + m];
      #pragma unroll
      for (int p=0;p<8;p++)
        acc[p] = fmaf(vS[t*64 + e0 + 8*p], kv, acc[p]);
      if (tid < 32) ks += kpS[t*32 + tid];
    }
  }
  int ob = (b*SEG + s);
  #pragma unroll
  for (int p=0;p<8;p++) kptvP[ob*2048 + tid + 256*p] = acc[p];
  if (tid<32) ksumP[ob*32 + tid] = ks;
}

// ---------------- R2: final reduce ----------------------------------------
__global__ void k_red2(const float* __restrict__ kptvP, const float* __restrict__ ksumP,
                       float* __restrict__ kptvF, float* __restrict__ ksumF){
  int b = blockIdx.x, tid = threadIdx.x;
  #pragma unroll
  for (int p=0;p<8;p++){
    int idx = tid + 256*p;
    float s = 0.f;
    for (int g=0; g<SEG; ++g) s += kptvP[(b*SEG+g)*2048 + idx];
    kptvF[b*2048+idx] = s;
  }
  if (tid<32){
    float s=0.f;
    for (int g=0; g<SEG; ++g) s += ksumP[(b*SEG+g)*32 + tid];
    ksumF[b*32+tid]=s;
  }
}

// ---------------- B (MFMA): attn + proj + LN2 + MLP, 64 tokens/block -------
// C/D layout: col=lane&15, row=quad*4+reg.  A: A[m=lane&15][k=quad*8+j].
// B: B[k=quad*8+j][n=lane&15].
__global__ __launch_bounds__(256,2) void k_b(
    const float* __restrict__ qp, const bf16* __restrict__ v,
    const float* __restrict__ kptvF, const float* __restrict__ ksumF,
    const float* __restrict__ wprojF, const float* __restrict__ bprojF,
    const float* __restrict__ g2F, const float* __restrict__ be2F,
    const float* __restrict__ wm1F, const float* __restrict__ bm1F,
    const float* __restrict__ wm2F, const float* __restrict__ bm2F,
    const int* __restrict__ flagp, void* __restrict__ outp)
{
  // pads: stride 40 (80B rows) and 72 (144B rows) are 16B-aligned, <=2-way banks (free)
  __shared__ __align__(16) bf16 qpS[64*40];     // qp A-tile        5120 B
  __shared__ __align__(16) bf16 kvS[64*40];     // kptv[e][m] B-tile 5120 B
  __shared__ __align__(16) bf16 w0S[64*72];     // wproj            9216 B
  __shared__ __align__(16) bf16 w1S[64*72];     // wm1              9216 B
  __shared__ __align__(16) bf16 w2S[64*72];     // wm2              9216 B
  __shared__ __align__(16) bf16 vS[64*72];      // v tile           9216 B
  __shared__ __align__(16) bf16 stA[64*72];     // staging ya/h     9216 B
  __shared__ __align__(16) bf16 stB[64*72];     // staging yn       9216 B
  __shared__ float ksS[32];
  __shared__ float DS[64];
  __shared__ float bpS[64], b1S[64], b2S[64], gS[64], btS[64];

  int flag = *flagp;
  int tid = threadIdx.x;
  int b = blockIdx.y;
  int gt0 = b*TT + blockIdx.x*64;

  // ---- stage all inputs ----
  // qp [64][32] fp32 -> bf16 LDS stride 40
  for (int i=tid; i<512; i+=256){
    int t = i>>3, q = i&7;
    float4 f = ((const float4*)qp)[(size_t)(gt0+t)*8 + q];
    union { bf16 h[4]; uint2 u; } cv;
    cv.h[0]=f2b(f.x); cv.h[1]=f2b(f.y); cv.h[2]=f2b(f.z); cv.h[3]=f2b(f.w);
    *((uint2*)&qpS[t*40 + q*4]) = cv.u;
  }
  // kptv [64][32] fp32 -> bf16 LDS stride 40
  for (int i=tid; i<512; i+=256){
    int e = i>>3, q = i&7;
    float4 f = ((const float4*)(kptvF + b*2048))[i];
    union { bf16 h[4]; uint2 u; } cv;
    cv.h[0]=f2b(f.x); cv.h[1]=f2b(f.y); cv.h[2]=f2b(f.z); cv.h[3]=f2b(f.w);
    *((uint2*)&kvS[e*40 + q*4]) = cv.u;
  }
  // v [64][64] bf16 -> LDS stride 72 (uint4 = 8 bf16 per (t,q), full 4096 elems)
  for (int i=tid; i<512; i+=256){
    int t = i>>3, q = i&7;
    uint4 u = ((const uint4*)(v + (size_t)gt0*64))[i];
    *((uint4*)&vS[t*72 + q*8]) = u;
  }
  // weights [64][64] fp32 -> bf16 LDS stride 72
  {
    const float* Wsrc[3] = {wprojF, wm1F, wm2F};
    bf16* Wdst[3] = {w0S, w1S, w2S};
    for (int w=0; w<3; ++w)
      for (int i=tid; i<1024; i+=256){
        int e = i>>4, q = i&15;
        float4 f = ((const float4*)Wsrc[w])[i];
        union { bf16 h[4]; uint2 u; } cv;
        cv.h[0]=f2b(f.x); cv.h[1]=f2b(f.y); cv.h[2]=f2b(f.z); cv.h[3]=f2b(f.w);
        *((uint2*)&Wdst[w][e*72 + q*4]) = cv.u;
      }
  }
  if (tid<32) ksS[tid] = ksumF[b*32+tid];
  if (tid<64){
    bpS[tid]=bprojF[tid]; b1S[tid]=bm1F[tid]; b2S[tid]=bm2F[tid];
    gS[tid]=g2F[tid]; btS[tid]=be2F[tid];
  }
  __syncthreads();   // S1

  int tw = tid>>6, lane = tid&63, quad = lane>>4, r = lane&15;
  int tRow = tw*16 + quad*4;               // +reg = local token row of C elems
  f4v zero = {0.f,0.f,0.f,0.f};

  // D[t] = sum_m qp[t][m]*ksum[m]  (wave 0, one token per lane)
  if (tid < 64){
    float s = 0.f;
    #pragma unroll
    for (int m=0; m<32; ++m) s = fmaf(b2f(qpS[tid*40+m]), ksS[m], s);
    DS[tid] = s;
  }

  // ---- attn GEMM: C[t][e] = sum_m qp[t][m] * kptv[e][m], K=32 ----
  f4v accA[4];
  {
    s8v aq = *((const s8v*)&qpS[(tw*16+r)*40 + quad*8]);
    #pragma unroll
    for (int nt=0; nt<4; ++nt){
      s8v bk = *((const s8v*)&kvS[(nt*16+r)*40 + quad*8]);
      accA[nt] = __builtin_amdgcn_mfma_f32_16x16x32_bf16(aq, bk, zero, 0,0,0);
    }
  }
  __syncthreads();   // S2 (DS visible)

  // ya = accA / (D+eps) -> stA (bf16, [t][e] stride 72)
  {
    float Dinv[4];
    #pragma unroll
    for (int reg=0; reg<4; ++reg) Dinv[reg] = 1.f/(DS[tRow+reg] + 1e-8f);
    #pragma unroll
    for (int nt=0; nt<4; ++nt)
      #pragma unroll
      for (int reg=0; reg<4; ++reg)
        stA[(tRow+reg)*72 + nt*16 + r] = f2b(accA[nt][reg]*Dinv[reg]);
  }
  __syncthreads();   // S3

  // ---- proj GEMM: y = v + ya @ wproj^T + bproj ----
  f4v accY[4] = {zero, zero, zero, zero};
  #pragma unroll
  for (int kh=0; kh<2; ++kh){
    s8v ay = *((const s8v*)&stA[(tw*16+r)*72 + kh*32 + quad*8]);
    #pragma unroll
    for (int nt=0; nt<4; ++nt){
      s8v bw = *((const s8v*)&w0S[(nt*16+r)*72 + kh*32 + quad*8]);
      accY[nt] = __builtin_amdgcn_mfma_f32_16x16x32_bf16(ay, bw, accY[nt], 0,0,0);
    }
  }
  float y[4][4];
  #pragma unroll
  for (int nt=0; nt<4; ++nt){
    int e = nt*16 + r;
    float bp = bpS[e];
    #pragma unroll
    for (int reg=0; reg<4; ++reg)
      y[nt][reg] = accY[nt][reg] + b2f(vS[(tRow+reg)*72 + e]) + bp;
  }

  // ---- LN2 (reduce across 16 lanes of the quad + 4 nt regs) ----
  float mu[4], rs[4];
  #pragma unroll
  for (int reg=0; reg<4; ++reg){
    float s = y[0][reg]+y[1][reg]+y[2][reg]+y[3][reg];
    #pragma unroll
    for (int off=1; off<16; off<<=1) s += __shfl_xor(s, off);
    mu[reg] = s * (1.f/64.f);
  }
  #pragma unroll
  for (int reg=0; reg<4; ++reg){
    float d2 = 0.f;
    #pragma unroll
    for (int nt=0; nt<4; ++nt){ float d = y[nt][reg]-mu[reg]; d2 = fmaf(d,d,d2); }
    #pragma unroll
    for (int off=1; off<16; off<<=1) d2 += __shfl_xor(d2, off);
    rs[reg] = rsqrtf(d2*(1.f/64.f) + 1e-5f);
  }
  #pragma unroll
  for (int nt=0; nt<4; ++nt){
    int e = nt*16 + r;
    float g = gS[e], be = btS[e];
    #pragma unroll
    for (int reg=0; reg<4; ++reg)
      stB[(tRow+reg)*72 + e] = f2b((y[nt][reg]-mu[reg])*rs[reg]*g + be);
  }
  __syncthreads();   // S4

  // ---- mlp1 GEMM + gelu ----
  f4v accH[4] = {zero, zero, zero, zero};
  #pragma unroll
  for (int kh=0; kh<2; ++kh){
    s8v ah = *((const s8v*)&stB[(tw*16+r)*72 + kh*32 + quad*8]);
    #pragma unroll
    for (int nt=0; nt<4; ++nt){
      s8v bw = *((const s8v*)&w1S[(nt*16+r)*72 + kh*32 + quad*8]);
      accH[nt] = __builtin_amdgcn_mfma_f32_16x16x32_bf16(ah, bw, accH[nt], 0,0,0);
    }
  }
  #pragma unroll
  for (int nt=0; nt<4; ++nt){
    int e = nt*16 + r;
    float b1 = b1S[e];
    #pragma unroll
    for (int reg=0; reg<4; ++reg){
      float h = accH[nt][reg] + b1;
      h = 0.5f*h*(1.f + erff(h*0.70710678118654752f));
      stA[(tRow+reg)*72 + e] = f2b(h);   // stA reads finished before S4
    }
  }
  __syncthreads();   // S5

  // ---- mlp2 GEMM + residual + store ----
  f4v accO[4] = {zero, zero, zero, zero};
  #pragma unroll
  for (int kh=0; kh<2; ++kh){
    s8v ao = *((const s8v*)&stA[(tw*16+r)*72 + kh*32 + quad*8]);
    #pragma unroll
    for (int nt=0; nt<4; ++nt){
      s8v bw = *((const s8v*)&w2S[(nt*16+r)*72 + kh*32 + quad*8]);
      accO[nt] = __builtin_amdgcn_mfma_f32_16x16x32_bf16(ao, bw, accO[nt], 0,0,0);
    }
  }
  if (flag){
    bf16* o = (bf16*)outp;
    #pragma unroll
    for (int nt=0; nt<4; ++nt){
      int e = nt*16 + r;
      float b2 = b2S[e];
      #pragma unroll
      for (int reg=0; reg<4; ++reg)
        o[(size_t)(gt0 + tRow + reg)*64 + e] = f2b(y[nt][reg] + accO[nt][reg] + b2);
    }
  } else {
    float* o = (float*)outp;
    #pragma unroll
    for (int nt=0; nt<4; ++nt){
      int e = nt*16 + r;
      float b2 = b2S[e];
      #pragma unroll
      for (int reg=0; reg<4; ++reg)
        o[(size_t)(gt0 + tRow + reg)*64 + e] = y[nt][reg] + accO[nt][reg] + b2;
    }
  }
}

// ---------------- launcher -------------------------------------------------
extern "C" void kernel_launch(void* const* d_in, const int* in_sizes, int n_in,
                              void* d_out, int out_size, void* d_ws, size_t ws_size,
                              hipStream_t stream){
  const void* x    = d_in[0];
  const void* wkqv = d_in[1];
  const void* bkqv = d_in[2];
  const void* wproj= d_in[3];
  const void* bproj= d_in[4];
  const void* g1   = d_in[5];
  const void* be1  = d_in[6];
  const void* g2   = d_in[7];
  const void* be2  = d_in[8];
  const void* wm1  = d_in[9];
  const void* bm1  = d_in[10];
  const void* wm2  = d_in[11];
  const void* bm2  = d_in[12];
  const void* Wrf  = d_in[13];

  char* ws = (char*)d_ws;
  int*   flagp = (int*)(ws + 0);
  float* wT    = (float*)(ws + 256);
  float* bkqvF = (float*)(ws + 113152);
  float* WrfF  = (float*)(ws + 113920);
  float* wprojF= (float*)(ws + 122112);
  float* bprojF= (float*)(ws + 138496);
  float* g2F   = (float*)(ws + 138752);
  float* be2F  = (float*)(ws + 139008);
  float* wm1F  = (float*)(ws + 139264);
  float* bm1F  = (float*)(ws + 155648);
  float* wm2F  = (float*)(ws + 155904);
  float* bm2F  = (float*)(ws + 172288);
  float* g1F   = (float*)(ws + 172544);
  float* be1F  = (float*)(ws + 173184);
  bf16*  xn    = (bf16*) (ws + 174080);
  float* kp    = (float*)(ws + 29677568);
  float* qp    = (float*)(ws + 42522624);
  bf16*  v     = (bf16*) (ws + 55367680);
  float* kptvP = (float*)(ws + 68212736);
  float* ksumP = (float*)(ws + 75552768);
  float* kptvF = (float*)(ws + 75667456);
  float* ksumF = (float*)(ws + 75929600);

  k_detect<<<1, 64, 0, stream>>>((const unsigned*)g1, flagp);
  k_cvt<<<170, 256, 0, stream>>>(wkqv, bkqv, Wrf, wproj, bproj, g2, be2,
      wm1, bm1, wm2, bm2, g1, be1, flagp,
      wT, bkqvF, WrfF, wprojF, bprojF, g2F, be2F, wm1F, bm1F, wm2F, bm2F, g1F, be1F);
  k_ln1<<<BT/4, 256, 0, stream>>>(x, g1F, be1F, flagp, xn);
  k_a2<<<BT/64, 256, 0, stream>>>(xn, wT, bkqvF, WrfF, kp, qp, v);
  k_red<<<dim3(SEG, BB), 256, 0, stream>>>(v, kp, kptvP, ksumP);
  k_red2<<<BB, 256, 0, stream>>>(kptvP, ksumP, kptvF, ksumF);
  k_b<<<dim3(TT/64, BB), 256, 0, stream>>>(qp, v, kptvF, ksumF,
      wprojF, bprojF, g2F, be2F, wm1F, bm1F, wm2F, bm2F, flagp, d_out);
}

// Round 5
// 291.435 us; speedup vs baseline: 3.4541x; 1.4487x over previous
//
#include <hip/hip_runtime.h>
#include <hip/hip_bf16.h>

#define BB 32
#define TT 3136
#define DD 147
#define EE 64
#define MM 32
#define BT (BB*TT)      // 100352
#define SEG 28
#define TSEG (TT/SEG)   // 112

typedef __hip_bfloat16 bf16;
typedef __attribute__((ext_vector_type(8))) short s8v;
typedef __attribute__((ext_vector_type(4))) float f4v;

__device__ __forceinline__ float b2f(bf16 v){ return __bfloat162float(v); }
__device__ __forceinline__ bf16 f2b(float v){ return __float2bfloat16(v); }

template<typename T>
__device__ __forceinline__ float cvt1(T v);
template<> __device__ __forceinline__ float cvt1<float>(float v){ return v; }
template<> __device__ __forceinline__ float cvt1<bf16>(bf16 v){ return __bfloat162float(v); }

// ---------------- detect: inputs bf16 (flag=1) or fp32 (flag=0) ------------
__global__ void k_detect(const unsigned* __restrict__ g1u, int* __restrict__ flagp){
  if (threadIdx.x == 0 && blockIdx.x == 0)
    *flagp = (g1u[0] == 0x3F803F80u) ? 1 : 0;
}

// ---------------- cvt: weights -> canonical layouts in ws ------------------
// Bprep bf16 [192][160]: Bprep[n][k] = wkqv[n][k], zero-padded k=147..159
// WrfB  bf16 [32][64]  : direct convert (row-major m,e)
template<typename T>
__device__ void cvt_body(int idx,
    const T* wkqv, const T* bkqv, const T* Wrf, const T* wproj, const T* bproj,
    const T* g2, const T* be2, const T* wm1, const T* bm1, const T* wm2,
    const T* bm2, const T* g1, const T* be1,
    bf16* Bprep, float* bkqvF, bf16* WrfB, float* wprojF, float* bprojF,
    float* g2F, float* be2F, float* wm1F, float* bm1F, float* wm2F,
    float* bm2F, float* g1F, float* be1F)
{
  if (idx < 30720){
    int n = idx/160, k = idx - n*160;
    Bprep[idx] = f2b(k < DD ? cvt1(wkqv[n*DD + k]) : 0.f);
    return;
  }
  idx -= 30720;
  if (idx < 192){ bkqvF[idx] = cvt1(bkqv[idx]); return; }
  idx -= 192;
  if (idx < 2048){ WrfB[idx] = f2b(cvt1(Wrf[idx])); return; }
  idx -= 2048;
  if (idx < 4096){ wprojF[idx] = cvt1(wproj[idx]); return; }
  idx -= 4096;
  if (idx < 64){ bprojF[idx] = cvt1(bproj[idx]); return; }
  idx -= 64;
  if (idx < 64){ g2F[idx] = cvt1(g2[idx]); return; }
  idx -= 64;
  if (idx < 64){ be2F[idx] = cvt1(be2[idx]); return; }
  idx -= 64;
  if (idx < 4096){ wm1F[idx] = cvt1(wm1[idx]); return; }
  idx -= 4096;
  if (idx < 64){ bm1F[idx] = cvt1(bm1[idx]); return; }
  idx -= 64;
  if (idx < 4096){ wm2F[idx] = cvt1(wm2[idx]); return; }
  idx -= 4096;
  if (idx < 64){ bm2F[idx] = cvt1(bm2[idx]); return; }
  idx -= 64;
  if (idx < DD){ g1F[idx] = cvt1(g1[idx]); return; }
  idx -= DD;
  if (idx < DD){ be1F[idx] = cvt1(be1[idx]); return; }
}

__global__ void k_cvt(const void* wkqv, const void* bkqv, const void* Wrf,
    const void* wproj, const void* bproj, const void* g2, const void* be2,
    const void* wm1, const void* bm1, const void* wm2, const void* bm2,
    const void* g1, const void* be1, const int* __restrict__ flagp,
    bf16* Bprep, float* bkqvF, bf16* WrfB, float* wprojF, float* bprojF,
    float* g2F, float* be2F, float* wm1F, float* bm1F, float* wm2F,
    float* bm2F, float* g1F, float* be1F)
{
  int idx = blockIdx.x*256 + threadIdx.x;
  if (*flagp)
    cvt_body<bf16>(idx, (const bf16*)wkqv, (const bf16*)bkqv, (const bf16*)Wrf,
      (const bf16*)wproj, (const bf16*)bproj, (const bf16*)g2, (const bf16*)be2,
      (const bf16*)wm1, (const bf16*)bm1, (const bf16*)wm2, (const bf16*)bm2,
      (const bf16*)g1, (const bf16*)be1,
      Bprep, bkqvF, WrfB, wprojF, bprojF, g2F, be2F, wm1F, bm1F, wm2F, bm2F, g1F, be1F);
  else
    cvt_body<float>(idx, (const float*)wkqv, (const float*)bkqv, (const float*)Wrf,
      (const float*)wproj, (const float*)bproj, (const float*)g2, (const float*)be2,
      (const float*)wm1, (const float*)bm1, (const float*)wm2, (const float*)bm2,
      (const float*)g1, (const float*)be1,
      Bprep, bkqvF, WrfB, wprojF, bprojF, g2F, be2F, wm1F, bm1F, wm2F, bm2F, g1F, be1F);
}

// ---------------- LN1: wave per token, output stride 160 (zero tail) -------
template<typename T>
__device__ void ln1_body(const T* __restrict__ x, const float* __restrict__ g1F,
                         const float* __restrict__ be1F, bf16* __restrict__ xn){
  int lane = threadIdx.x & 63;
  int t = blockIdx.x*4 + (threadIdx.x>>6);
  size_t base = (size_t)t*DD;
  float v0 = cvt1(x[base+lane]);
  float v1 = cvt1(x[base+64+lane]);
  float v2 = (lane < DD-128) ? cvt1(x[base+128+lane]) : 0.f;
  float s = v0+v1+v2, s2 = v0*v0+v1*v1+v2*v2;
  #pragma unroll
  for (int off=32; off; off>>=1){ s += __shfl_xor(s,off); s2 += __shfl_xor(s2,off); }
  float mu  = s * (1.f/147.f);
  float var = s2 * (1.f/147.f) - mu*mu;
  float r = rsqrtf(var + 1e-5f);
  bf16* xo = xn + (size_t)t*160;
  xo[lane]    = f2b((v0-mu)*r*g1F[lane]    + be1F[lane]);
  xo[64+lane] = f2b((v1-mu)*r*g1F[64+lane] + be1F[64+lane]);
  if (lane < 32)
    xo[128+lane] = (lane < DD-128)
      ? f2b((v2-mu)*r*g1F[128+lane] + be1F[128+lane]) : f2b(0.f);
}

__global__ void k_ln1(const void* __restrict__ x, const float* __restrict__ g1F,
                      const float* __restrict__ be1F, const int* __restrict__ flagp,
                      bf16* __restrict__ xn){
  if (*flagp) ln1_body<bf16>((const bf16*)x, g1F, be1F, xn);
  else        ln1_body<float>((const float*)x, g1F, be1F, xn);
}

// ---------------- A2 (MFMA): kqv GEMM + prm_exp epilogue -------------------
// C/D: col=lane&15, row=quad*4+reg.  A: A[m=lane&15][k=quad*8+j].
// B: B[k=quad*8+j][n=lane&15].
// Block = 64 tokens; wave tw owns tokens tw*16..tw*16+15 (full 192 channels).
__global__ __launch_bounds__(256) void k_a2(
    const bf16* __restrict__ xn, const bf16* __restrict__ Bprep,
    const float* __restrict__ bkqvF, const bf16* __restrict__ WrfB,
    float* __restrict__ kp, float* __restrict__ qp, bf16* __restrict__ v)
{
  __shared__ __align__(16) bf16 aS[64*168];   // xn tile, stride 168 (2-way banks, free)
  __shared__ __align__(16) bf16 kqS[64*136];  // biased k,q tile, stride 136 (2-way, free)

  int tid = threadIdx.x;
  size_t t0 = (size_t)blockIdx.x*64;

  // stage A tile: 64 rows x 160 bf16 = 1280 uint4
  const uint4* xg = (const uint4*)(xn + t0*160);
  for (int i=tid; i<1280; i+=256){
    int row = i/20, ch = i - row*20;
    uint4 u = xg[i];
    *((uint4*)&aS[row*168 + ch*8]) = u;
  }
  __syncthreads();

  int tw = tid>>6, lane = tid&63, quad = lane>>4, r = lane&15;
  int tRow = tw*16 + quad*4;
  f4v zero = {0.f,0.f,0.f,0.f};

  // ---- main GEMM: kqv[t][n] = sum_k xn[t][k] * wkqv[n][k], K=160 ----
  f4v acc[12];
  #pragma unroll
  for (int nt=0; nt<12; ++nt) acc[nt] = zero;
  const bf16* aBase = &aS[(tw*16+r)*168 + quad*8];
  const bf16* bBase = &Bprep[r*160 + quad*8];
  #pragma unroll 1
  for (int ks=0; ks<5; ++ks){
    s8v a = *((const s8v*)(aBase + ks*32));
    #pragma unroll
    for (int nt=0; nt<12; ++nt){
      s8v bw = *((const s8v*)(bBase + nt*16*160 + ks*32));
      acc[nt] = __builtin_amdgcn_mfma_f32_16x16x32_bf16(a, bw, acc[nt], 0,0,0);
    }
  }

  float bias[12];
  #pragma unroll
  for (int nt=0; nt<12; ++nt) bias[nt] = bkqvF[nt*16 + r];

  // v out (channels 128..191)
  #pragma unroll
  for (int nt=8; nt<12; ++nt){
    #pragma unroll
    for (int reg=0; reg<4; ++reg)
      v[(t0 + tRow + reg)*64 + (nt-8)*16 + r] = f2b(acc[nt][reg] + bias[nt]);
  }

  // biased k,q
  float kq[8][4];
  #pragma unroll
  for (int nt=0; nt<8; ++nt)
    #pragma unroll
    for (int reg=0; reg<4; ++reg)
      kq[nt][reg] = acc[nt][reg] + bias[nt];

  // kq -> LDS [t][0..127] stride 136 (each wave touches only its own strip)
  #pragma unroll
  for (int nt=0; nt<8; ++nt)
    #pragma unroll
    for (int reg=0; reg<4; ++reg)
      kqS[(tRow+reg)*136 + nt*16 + r] = f2b(kq[nt][reg]);

  // xd = 0.5*||.||^2 per token row (reduce 4 cols/lane, then 16 lanes)
  float xdk[4], xdq[4];
  #pragma unroll
  for (int reg=0; reg<4; ++reg){
    float sk = 0.f, sq = 0.f;
    #pragma unroll
    for (int nt=0; nt<4; ++nt){
      sk = fmaf(kq[nt][reg],   kq[nt][reg],   sk);
      sq = fmaf(kq[nt+4][reg], kq[nt+4][reg], sq);
    }
    #pragma unroll
    for (int off=1; off<16; off<<=1){
      sk += __shfl_xor(sk, off);
      sq += __shfl_xor(sq, off);
    }
    xdk[reg] = 0.5f*sk;
    xdq[reg] = 0.5f*sq;
  }
  __syncthreads();

  // ---- prm_exp GEMM: pre[t][m] = sum_e kq[t][e] * Wrf[m][e], K=64 ----
  f4v accP[2] = {zero, zero}, accQ[2] = {zero, zero};
  #pragma unroll
  for (int ks=0; ks<2; ++ks){
    s8v ak = *((const s8v*)&kqS[(tw*16+r)*136 + ks*32 + quad*8]);
    s8v aq = *((const s8v*)&kqS[(tw*16+r)*136 + 64 + ks*32 + quad*8]);
    #pragma unroll
    for (int nt=0; nt<2; ++nt){
      s8v wf = *((const s8v*)&WrfB[(nt*16+r)*64 + ks*32 + quad*8]);
      accP[nt] = __builtin_amdgcn_mfma_f32_16x16x32_bf16(ak, wf, accP[nt], 0,0,0);
      accQ[nt] = __builtin_amdgcn_mfma_f32_16x16x32_bf16(aq, wf, accQ[nt], 0,0,0);
    }
  }
  #pragma unroll
  for (int nt=0; nt<2; ++nt){
    #pragma unroll
    for (int reg=0; reg<4; ++reg){
      size_t gt = t0 + tRow + reg;
      kp[gt*32 + nt*16 + r] = expf(accP[nt][reg] - xdk[reg]) * 0.17677669529663687f;
      qp[gt*32 + nt*16 + r] = expf(accQ[nt][reg] - xdq[reg]) * 0.17677669529663687f;
    }
  }
}

// ---------------- R1: partial kptv/ksum over 112-token segments ------------
__global__ void k_red(const bf16* __restrict__ v, const float* __restrict__ kp,
                      float* __restrict__ kptvP, float* __restrict__ ksumP){
  __shared__ float vS[16*64];
  __shared__ float kpS[16*32];
  int tid = threadIdx.x;
  int s = blockIdx.x, b = blockIdx.y;
  int tbase = b*TT + s*TSEG;
  float acc[8];
  #pragma unroll
  for (int p=0;p<8;p++) acc[p]=0.f;
  float ks = 0.f;
  int m  = tid & 31;
  int e0 = tid >> 5;
  for (int c=0;c<7;c++){
    __syncthreads();
    for (int idx=tid; idx<1024; idx+=256)
      vS[idx] = b2f(v[(size_t)(tbase + c*16 + (idx>>6))*64 + (idx&63)]);
    for (int idx=tid; idx<512; idx+=256)
      kpS[idx] = kp[(size_t)(tbase + c*16 + (idx>>5))*32 + (idx&31)];
    __syncthreads();
    #pragma unroll 4
    for (int t=0;t<16;t++){
      float kv = kpS[t*32 + m];
      #pragma unroll
      for (int p=0;p<8;p++)
        acc[p] = fmaf(vS[t*64 + e0 + 8*p], kv, acc[p]);
      if (tid < 32) ks += kpS[t*32 + tid];
    }
  }
  int ob = (b*SEG + s);
  #pragma unroll
  for (int p=0;p<8;p++) kptvP[ob*2048 + tid + 256*p] = acc[p];
  if (tid<32) ksumP[ob*32 + tid] = ks;
}

// ---------------- R2: final reduce ----------------------------------------
__global__ void k_red2(const float* __restrict__ kptvP, const float* __restrict__ ksumP,
                       float* __restrict__ kptvF, float* __restrict__ ksumF){
  int b = blockIdx.x, tid = threadIdx.x;
  #pragma unroll
  for (int p=0;p<8;p++){
    int idx = tid + 256*p;
    float s = 0.f;
    for (int g=0; g<SEG; ++g) s += kptvP[(b*SEG+g)*2048 + idx];
    kptvF[b*2048+idx] = s;
  }
  if (tid<32){
    float s=0.f;
    for (int g=0; g<SEG; ++g) s += ksumP[(b*SEG+g)*32 + tid];
    ksumF[b*32+tid]=s;
  }
}

// ---------------- B (MFMA): attn + proj + LN2 + MLP, 64 tokens/block -------
__global__ __launch_bounds__(256,2) void k_b(
    const float* __restrict__ qp, const bf16* __restrict__ v,
    const float* __restrict__ kptvF, const float* __restrict__ ksumF,
    const float* __restrict__ wprojF, const float* __restrict__ bprojF,
    const float* __restrict__ g2F, const float* __restrict__ be2F,
    const float* __restrict__ wm1F, const float* __restrict__ bm1F,
    const float* __restrict__ wm2F, const float* __restrict__ bm2F,
    const int* __restrict__ flagp, void* __restrict__ outp)
{
  __shared__ __align__(16) bf16 qpS[64*40];
  __shared__ __align__(16) bf16 kvS[64*40];
  __shared__ __align__(16) bf16 w0S[64*72];
  __shared__ __align__(16) bf16 w1S[64*72];
  __shared__ __align__(16) bf16 w2S[64*72];
  __shared__ __align__(16) bf16 vS[64*72];
  __shared__ __align__(16) bf16 stA[64*72];
  __shared__ __align__(16) bf16 stB[64*72];
  __shared__ float ksS[32];
  __shared__ float DS[64];
  __shared__ float bpS[64], b1S[64], b2S[64], gS[64], btS[64];

  int flag = *flagp;
  int tid = threadIdx.x;
  int b = blockIdx.y;
  int gt0 = b*TT + blockIdx.x*64;

  for (int i=tid; i<512; i+=256){
    int t = i>>3, q = i&7;
    float4 f = ((const float4*)qp)[(size_t)(gt0+t)*8 + q];
    union { bf16 h[4]; uint2 u; } cv;
    cv.h[0]=f2b(f.x); cv.h[1]=f2b(f.y); cv.h[2]=f2b(f.z); cv.h[3]=f2b(f.w);
    *((uint2*)&qpS[t*40 + q*4]) = cv.u;
  }
  for (int i=tid; i<512; i+=256){
    int e = i>>3, q = i&7;
    float4 f = ((const float4*)(kptvF + b*2048))[i];
    union { bf16 h[4]; uint2 u; } cv;
    cv.h[0]=f2b(f.x); cv.h[1]=f2b(f.y); cv.h[2]=f2b(f.z); cv.h[3]=f2b(f.w);
    *((uint2*)&kvS[e*40 + q*4]) = cv.u;
  }
  for (int i=tid; i<512; i+=256){
    int t = i>>3, q = i&7;
    uint4 u = ((const uint4*)(v + (size_t)gt0*64))[i];
    *((uint4*)&vS[t*72 + q*8]) = u;
  }
  {
    const float* Wsrc[3] = {wprojF, wm1F, wm2F};
    bf16* Wdst[3] = {w0S, w1S, w2S};
    for (int w=0; w<3; ++w)
      for (int i=tid; i<1024; i+=256){
        int e = i>>4, q = i&15;
        float4 f = ((const float4*)Wsrc[w])[i];
        union { bf16 h[4]; uint2 u; } cv;
        cv.h[0]=f2b(f.x); cv.h[1]=f2b(f.y); cv.h[2]=f2b(f.z); cv.h[3]=f2b(f.w);
        *((uint2*)&Wdst[w][e*72 + q*4]) = cv.u;
      }
  }
  if (tid<32) ksS[tid] = ksumF[b*32+tid];
  if (tid<64){
    bpS[tid]=bprojF[tid]; b1S[tid]=bm1F[tid]; b2S[tid]=bm2F[tid];
    gS[tid]=g2F[tid]; btS[tid]=be2F[tid];
  }
  __syncthreads();   // S1

  int tw = tid>>6, lane = tid&63, quad = lane>>4, r = lane&15;
  int tRow = tw*16 + quad*4;
  f4v zero = {0.f,0.f,0.f,0.f};

  if (tid < 64){
    float s = 0.f;
    #pragma unroll
    for (int m=0; m<32; ++m) s = fmaf(b2f(qpS[tid*40+m]), ksS[m], s);
    DS[tid] = s;
  }

  f4v accA[4];
  {
    s8v aq = *((const s8v*)&qpS[(tw*16+r)*40 + quad*8]);
    #pragma unroll
    for (int nt=0; nt<4; ++nt){
      s8v bk = *((const s8v*)&kvS[(nt*16+r)*40 + quad*8]);
      accA[nt] = __builtin_amdgcn_mfma_f32_16x16x32_bf16(aq, bk, zero, 0,0,0);
    }
  }
  __syncthreads();   // S2

  {
    float Dinv[4];
    #pragma unroll
    for (int reg=0; reg<4; ++reg) Dinv[reg] = 1.f/(DS[tRow+reg] + 1e-8f);
    #pragma unroll
    for (int nt=0; nt<4; ++nt)
      #pragma unroll
      for (int reg=0; reg<4; ++reg)
        stA[(tRow+reg)*72 + nt*16 + r] = f2b(accA[nt][reg]*Dinv[reg]);
  }
  __syncthreads();   // S3

  f4v accY[4] = {zero, zero, zero, zero};
  #pragma unroll
  for (int kh=0; kh<2; ++kh){
    s8v ay = *((const s8v*)&stA[(tw*16+r)*72 + kh*32 + quad*8]);
    #pragma unroll
    for (int nt=0; nt<4; ++nt){
      s8v bw = *((const s8v*)&w0S[(nt*16+r)*72 + kh*32 + quad*8]);
      accY[nt] = __builtin_amdgcn_mfma_f32_16x16x32_bf16(ay, bw, accY[nt], 0,0,0);
    }
  }
  float y[4][4];
  #pragma unroll
  for (int nt=0; nt<4; ++nt){
    int e = nt*16 + r;
    float bp = bpS[e];
    #pragma unroll
    for (int reg=0; reg<4; ++reg)
      y[nt][reg] = accY[nt][reg] + b2f(vS[(tRow+reg)*72 + e]) + bp;
  }

  float mu[4], rs[4];
  #pragma unroll
  for (int reg=0; reg<4; ++reg){
    float s = y[0][reg]+y[1][reg]+y[2][reg]+y[3][reg];
    #pragma unroll
    for (int off=1; off<16; off<<=1) s += __shfl_xor(s, off);
    mu[reg] = s * (1.f/64.f);
  }
  #pragma unroll
  for (int reg=0; reg<4; ++reg){
    float d2 = 0.f;
    #pragma unroll
    for (int nt=0; nt<4; ++nt){ float d = y[nt][reg]-mu[reg]; d2 = fmaf(d,d,d2); }
    #pragma unroll
    for (int off=1; off<16; off<<=1) d2 += __shfl_xor(d2, off);
    rs[reg] = rsqrtf(d2*(1.f/64.f) + 1e-5f);
  }
  #pragma unroll
  for (int nt=0; nt<4; ++nt){
    int e = nt*16 + r;
    float g = gS[e], be = btS[e];
    #pragma unroll
    for (int reg=0; reg<4; ++reg)
      stB[(tRow+reg)*72 + e] = f2b((y[nt][reg]-mu[reg])*rs[reg]*g + be);
  }
  __syncthreads();   // S4

  f4v accH[4] = {zero, zero, zero, zero};
  #pragma unroll
  for (int kh=0; kh<2; ++kh){
    s8v ah = *((const s8v*)&stB[(tw*16+r)*72 + kh*32 + quad*8]);
    #pragma unroll
    for (int nt=0; nt<4; ++nt){
      s8v bw = *((const s8v*)&w1S[(nt*16+r)*72 + kh*32 + quad*8]);
      accH[nt] = __builtin_amdgcn_mfma_f32_16x16x32_bf16(ah, bw, accH[nt], 0,0,0);
    }
  }
  #pragma unroll
  for (int nt=0; nt<4; ++nt){
    int e = nt*16 + r;
    float b1 = b1S[e];
    #pragma unroll
    for (int reg=0; reg<4; ++reg){
      float h = accH[nt][reg] + b1;
      h = 0.5f*h*(1.f + erff(h*0.70710678118654752f));
      stA[(tRow+reg)*72 + e] = f2b(h);
    }
  }
  __syncthreads();   // S5

  f4v accO[4] = {zero, zero, zero, zero};
  #pragma unroll
  for (int kh=0; kh<2; ++kh){
    s8v ao = *((const s8v*)&stA[(tw*16+r)*72 + kh*32 + quad*8]);
    #pragma unroll
    for (int nt=0; nt<4; ++nt){
      s8v bw = *((const s8v*)&w2S[(nt*16+r)*72 + kh*32 + quad*8]);
      accO[nt] = __builtin_amdgcn_mfma_f32_16x16x32_bf16(ao, bw, accO[nt], 0,0,0);
    }
  }
  if (flag){
    bf16* o = (bf16*)outp;
    #pragma unroll
    for (int nt=0; nt<4; ++nt){
      int e = nt*16 + r;
      float b2 = b2S[e];
      #pragma unroll
      for (int reg=0; reg<4; ++reg)
        o[(size_t)(gt0 + tRow + reg)*64 + e] = f2b(y[nt][reg] + accO[nt][reg] + b2);
    }
  } else {
    float* o = (float*)outp;
    #pragma unroll
    for (int nt=0; nt<4; ++nt){
      int e = nt*16 + r;
      float b2 = b2S[e];
      #pragma unroll
      for (int reg=0; reg<4; ++reg)
        o[(size_t)(gt0 + tRow + reg)*64 + e] = y[nt][reg] + accO[nt][reg] + b2;
    }
  }
}

// ---------------- launcher -------------------------------------------------
extern "C" void kernel_launch(void* const* d_in, const int* in_sizes, int n_in,
                              void* d_out, int out_size, void* d_ws, size_t ws_size,
                              hipStream_t stream){
  const void* x    = d_in[0];
  const void* wkqv = d_in[1];
  const void* bkqv = d_in[2];
  const void* wproj= d_in[3];
  const void* bproj= d_in[4];
  const void* g1   = d_in[5];
  const void* be1  = d_in[6];
  const void* g2   = d_in[7];
  const void* be2  = d_in[8];
  const void* wm1  = d_in[9];
  const void* bm1  = d_in[10];
  const void* wm2  = d_in[11];
  const void* bm2  = d_in[12];
  const void* Wrf  = d_in[13];

  char* ws = (char*)d_ws;
  int*   flagp = (int*)(ws + 0);
  bf16*  Bprep = (bf16*) (ws + 256);
  float* bkqvF = (float*)(ws + 61696);
  bf16*  WrfB  = (bf16*) (ws + 62464);
  float* wprojF= (float*)(ws + 66560);
  float* bprojF= (float*)(ws + 82944);
  float* g2F   = (float*)(ws + 83200);
  float* be2F  = (float*)(ws + 83456);
  float* wm1F  = (float*)(ws + 83712);
  float* bm1F  = (float*)(ws + 100096);
  float* wm2F  = (float*)(ws + 100352);
  float* bm2F  = (float*)(ws + 116736);
  float* g1F   = (float*)(ws + 116992);
  float* be1F  = (float*)(ws + 117760);
  bf16*  xn    = (bf16*) (ws + 118784);            // BT*160*2 = 32112640 B
  // alias into dead xn region (k_red runs after k_a2's last xn read):
  float* kptvP = (float*)(ws + 118784);            // 7340032 B
  float* ksumP = (float*)(ws + 7458816);           // 114688 B
  float* kptvF = (float*)(ws + 7573504);           // 262144 B
  float* ksumF = (float*)(ws + 7835648);           // 4096 B
  float* kp    = (float*)(ws + 32231424);          // 12845056 B
  float* qp    = (float*)(ws + 45076480);          // 12845056 B
  bf16*  v     = (bf16*) (ws + 57921536);          // 12845056 B -> end 70766592

  k_detect<<<1, 64, 0, stream>>>((const unsigned*)g1, flagp);
  k_cvt<<<180, 256, 0, stream>>>(wkqv, bkqv, Wrf, wproj, bproj, g2, be2,
      wm1, bm1, wm2, bm2, g1, be1, flagp,
      Bprep, bkqvF, WrfB, wprojF, bprojF, g2F, be2F, wm1F, bm1F, wm2F, bm2F, g1F, be1F);
  k_ln1<<<BT/4, 256, 0, stream>>>(x, g1F, be1F, flagp, xn);
  k_a2<<<BT/64, 256, 0, stream>>>(xn, Bprep, bkqvF, WrfB, kp, qp, v);
  k_red<<<dim3(SEG, BB), 256, 0, stream>>>(v, kp, kptvP, ksumP);
  k_red2<<<BB, 256, 0, stream>>>(kptvP, ksumP, kptvF, ksumF);
  k_b<<<dim3(TT/64, BB), 256, 0, stream>>>(qp, v, kptvF, ksumF,
      wprojF, bprojF, g2F, be2F, wm1F, bm1F, wm2F, bm2F, flagp, d_out);
}

// Round 6
// 243.763 us; speedup vs baseline: 4.1296x; 1.1956x over previous
//
#include <hip/hip_runtime.h>
#include <hip/hip_bf16.h>

#define BB 32
#define TT 3136
#define DD 147
#define EE 64
#define MM 32
#define BT (BB*TT)      // 100352
#define SEG 28
#define TSEG (TT/SEG)   // 112

typedef __hip_bfloat16 bf16;
typedef __attribute__((ext_vector_type(8))) short s8v;
typedef __attribute__((ext_vector_type(4))) float f4v;

__device__ __forceinline__ float b2f(bf16 v){ return __bfloat162float(v); }
__device__ __forceinline__ bf16 f2b(float v){ return __float2bfloat16(v); }

template<typename T>
__device__ __forceinline__ float cvt1(T v);
template<> __device__ __forceinline__ float cvt1<float>(float v){ return v; }
template<> __device__ __forceinline__ float cvt1<bf16>(bf16 v){ return __bfloat162float(v); }

// ---------------- detect: inputs bf16 (flag=1) or fp32 (flag=0) ------------
__global__ void k_detect(const unsigned* __restrict__ g1u, int* __restrict__ flagp){
  if (threadIdx.x == 0 && blockIdx.x == 0)
    *flagp = (g1u[0] == 0x3F803F80u) ? 1 : 0;
}

// ---------------- cvt: weights -> canonical layouts in ws ------------------
// Bprep bf16 [192][160]: Bprep[n][k] = wkqv[n][k], zero-padded k=147..159
// WrfB  bf16 [32][64]  : direct convert (row-major m,e)
template<typename T>
__device__ void cvt_body(int idx,
    const T* wkqv, const T* bkqv, const T* Wrf, const T* wproj, const T* bproj,
    const T* g2, const T* be2, const T* wm1, const T* bm1, const T* wm2,
    const T* bm2, const T* g1, const T* be1,
    bf16* Bprep, float* bkqvF, bf16* WrfB, float* wprojF, float* bprojF,
    float* g2F, float* be2F, float* wm1F, float* bm1F, float* wm2F,
    float* bm2F, float* g1F, float* be1F)
{
  if (idx < 30720){
    int n = idx/160, k = idx - n*160;
    Bprep[idx] = f2b(k < DD ? cvt1(wkqv[n*DD + k]) : 0.f);
    return;
  }
  idx -= 30720;
  if (idx < 192){ bkqvF[idx] = cvt1(bkqv[idx]); return; }
  idx -= 192;
  if (idx < 2048){ WrfB[idx] = f2b(cvt1(Wrf[idx])); return; }
  idx -= 2048;
  if (idx < 4096){ wprojF[idx] = cvt1(wproj[idx]); return; }
  idx -= 4096;
  if (idx < 64){ bprojF[idx] = cvt1(bproj[idx]); return; }
  idx -= 64;
  if (idx < 64){ g2F[idx] = cvt1(g2[idx]); return; }
  idx -= 64;
  if (idx < 64){ be2F[idx] = cvt1(be2[idx]); return; }
  idx -= 64;
  if (idx < 4096){ wm1F[idx] = cvt1(wm1[idx]); return; }
  idx -= 4096;
  if (idx < 64){ bm1F[idx] = cvt1(bm1[idx]); return; }
  idx -= 64;
  if (idx < 4096){ wm2F[idx] = cvt1(wm2[idx]); return; }
  idx -= 4096;
  if (idx < 64){ bm2F[idx] = cvt1(bm2[idx]); return; }
  idx -= 64;
  if (idx < DD){ g1F[idx] = cvt1(g1[idx]); return; }
  idx -= DD;
  if (idx < DD){ be1F[idx] = cvt1(be1[idx]); return; }
}

__global__ void k_cvt(const void* wkqv, const void* bkqv, const void* Wrf,
    const void* wproj, const void* bproj, const void* g2, const void* be2,
    const void* wm1, const void* bm1, const void* wm2, const void* bm2,
    const void* g1, const void* be1, const int* __restrict__ flagp,
    bf16* Bprep, float* bkqvF, bf16* WrfB, float* wprojF, float* bprojF,
    float* g2F, float* be2F, float* wm1F, float* bm1F, float* wm2F,
    float* bm2F, float* g1F, float* be1F)
{
  int idx = blockIdx.x*256 + threadIdx.x;
  if (*flagp)
    cvt_body<bf16>(idx, (const bf16*)wkqv, (const bf16*)bkqv, (const bf16*)Wrf,
      (const bf16*)wproj, (const bf16*)bproj, (const bf16*)g2, (const bf16*)be2,
      (const bf16*)wm1, (const bf16*)bm1, (const bf16*)wm2, (const bf16*)bm2,
      (const bf16*)g1, (const bf16*)be1,
      Bprep, bkqvF, WrfB, wprojF, bprojF, g2F, be2F, wm1F, bm1F, wm2F, bm2F, g1F, be1F);
  else
    cvt_body<float>(idx, (const float*)wkqv, (const float*)bkqv, (const float*)Wrf,
      (const float*)wproj, (const float*)bproj, (const float*)g2, (const float*)be2,
      (const float*)wm1, (const float*)bm1, (const float*)wm2, (const float*)bm2,
      (const float*)g1, (const float*)be1,
      Bprep, bkqvF, WrfB, wprojF, bprojF, g2F, be2F, wm1F, bm1F, wm2F, bm2F, g1F, be1F);
}

// ---------------- LN1: wave per token, output stride 160 (zero tail) -------
template<typename T>
__device__ void ln1_body(const T* __restrict__ x, const float* __restrict__ g1F,
                         const float* __restrict__ be1F, bf16* __restrict__ xn){
  int lane = threadIdx.x & 63;
  int t = blockIdx.x*4 + (threadIdx.x>>6);
  size_t base = (size_t)t*DD;
  float v0 = cvt1(x[base+lane]);
  float v1 = cvt1(x[base+64+lane]);
  float v2 = (lane < DD-128) ? cvt1(x[base+128+lane]) : 0.f;
  float s = v0+v1+v2, s2 = v0*v0+v1*v1+v2*v2;
  #pragma unroll
  for (int off=32; off; off>>=1){ s += __shfl_xor(s,off); s2 += __shfl_xor(s2,off); }
  float mu  = s * (1.f/147.f);
  float var = s2 * (1.f/147.f) - mu*mu;
  float r = rsqrtf(var + 1e-5f);
  bf16* xo = xn + (size_t)t*160;
  xo[lane]    = f2b((v0-mu)*r*g1F[lane]    + be1F[lane]);
  xo[64+lane] = f2b((v1-mu)*r*g1F[64+lane] + be1F[64+lane]);
  if (lane < 32)
    xo[128+lane] = (lane < DD-128)
      ? f2b((v2-mu)*r*g1F[128+lane] + be1F[128+lane]) : f2b(0.f);
}

__global__ void k_ln1(const void* __restrict__ x, const float* __restrict__ g1F,
                      const float* __restrict__ be1F, const int* __restrict__ flagp,
                      bf16* __restrict__ xn){
  if (*flagp) ln1_body<bf16>((const bf16*)x, g1F, be1F, xn);
  else        ln1_body<float>((const float*)x, g1F, be1F, xn);
}

// ---------------- A2 (MFMA): kqv GEMM + prm_exp epilogue -------------------
// C/D: col=lane&15, row=quad*4+reg.  A: A[m=lane&15][k=quad*8+j].
// B: B[k=quad*8+j][n=lane&15].
// Block = 64 tokens; wave tw owns tokens tw*16..tw*16+15 (full 192 channels).
__global__ __launch_bounds__(256) void k_a2(
    const bf16* __restrict__ xn, const bf16* __restrict__ Bprep,
    const float* __restrict__ bkqvF, const bf16* __restrict__ WrfB,
    float* __restrict__ kp, float* __restrict__ qp, bf16* __restrict__ v)
{
  __shared__ __align__(16) bf16 aS[64*168];   // xn tile, stride 168 (2-way banks, free)
  __shared__ __align__(16) bf16 kqS[64*136];  // biased k,q tile, stride 136 (2-way, free)

  int tid = threadIdx.x;
  size_t t0 = (size_t)blockIdx.x*64;

  // stage A tile: 64 rows x 160 bf16 = 1280 uint4
  const uint4* xg = (const uint4*)(xn + t0*160);
  for (int i=tid; i<1280; i+=256){
    int row = i/20, ch = i - row*20;
    uint4 u = xg[i];
    *((uint4*)&aS[row*168 + ch*8]) = u;
  }
  __syncthreads();

  int tw = tid>>6, lane = tid&63, quad = lane>>4, r = lane&15;
  int tRow = tw*16 + quad*4;
  f4v zero = {0.f,0.f,0.f,0.f};

  // ---- main GEMM: kqv[t][n] = sum_k xn[t][k] * wkqv[n][k], K=160 ----
  f4v acc[12];
  #pragma unroll
  for (int nt=0; nt<12; ++nt) acc[nt] = zero;
  const bf16* aBase = &aS[(tw*16+r)*168 + quad*8];
  const bf16* bBase = &Bprep[r*160 + quad*8];
  #pragma unroll 1
  for (int ks=0; ks<5; ++ks){
    s8v a = *((const s8v*)(aBase + ks*32));
    #pragma unroll
    for (int nt=0; nt<12; ++nt){
      s8v bw = *((const s8v*)(bBase + nt*16*160 + ks*32));
      acc[nt] = __builtin_amdgcn_mfma_f32_16x16x32_bf16(a, bw, acc[nt], 0,0,0);
    }
  }

  float bias[12];
  #pragma unroll
  for (int nt=0; nt<12; ++nt) bias[nt] = bkqvF[nt*16 + r];

  // v out (channels 128..191)
  #pragma unroll
  for (int nt=8; nt<12; ++nt){
    #pragma unroll
    for (int reg=0; reg<4; ++reg)
      v[(t0 + tRow + reg)*64 + (nt-8)*16 + r] = f2b(acc[nt][reg] + bias[nt]);
  }

  // biased k,q
  float kq[8][4];
  #pragma unroll
  for (int nt=0; nt<8; ++nt)
    #pragma unroll
    for (int reg=0; reg<4; ++reg)
      kq[nt][reg] = acc[nt][reg] + bias[nt];

  // kq -> LDS [t][0..127] stride 136 (each wave touches only its own strip)
  #pragma unroll
  for (int nt=0; nt<8; ++nt)
    #pragma unroll
    for (int reg=0; reg<4; ++reg)
      kqS[(tRow+reg)*136 + nt*16 + r] = f2b(kq[nt][reg]);

  // xd = 0.5*||.||^2 per token row (reduce 4 cols/lane, then 16 lanes)
  float xdk[4], xdq[4];
  #pragma unroll
  for (int reg=0; reg<4; ++reg){
    float sk = 0.f, sq = 0.f;
    #pragma unroll
    for (int nt=0; nt<4; ++nt){
      sk = fmaf(kq[nt][reg],   kq[nt][reg],   sk);
      sq = fmaf(kq[nt+4][reg], kq[nt+4][reg], sq);
    }
    #pragma unroll
    for (int off=1; off<16; off<<=1){
      sk += __shfl_xor(sk, off);
      sq += __shfl_xor(sq, off);
    }
    xdk[reg] = 0.5f*sk;
    xdq[reg] = 0.5f*sq;
  }
  __syncthreads();

  // ---- prm_exp GEMM: pre[t][m] = sum_e kq[t][e] * Wrf[m][e], K=64 ----
  f4v accP[2] = {zero, zero}, accQ[2] = {zero, zero};
  #pragma unroll
  for (int ks=0; ks<2; ++ks){
    s8v ak = *((const s8v*)&kqS[(tw*16+r)*136 + ks*32 + quad*8]);
    s8v aq = *((const s8v*)&kqS[(tw*16+r)*136 + 64 + ks*32 + quad*8]);
    #pragma unroll
    for (int nt=0; nt<2; ++nt){
      s8v wf = *((const s8v*)&WrfB[(nt*16+r)*64 + ks*32 + quad*8]);
      accP[nt] = __builtin_amdgcn_mfma_f32_16x16x32_bf16(ak, wf, accP[nt], 0,0,0);
      accQ[nt] = __builtin_amdgcn_mfma_f32_16x16x32_bf16(aq, wf, accQ[nt], 0,0,0);
    }
  }
  #pragma unroll
  for (int nt=0; nt<2; ++nt){
    #pragma unroll
    for (int reg=0; reg<4; ++reg){
      size_t gt = t0 + tRow + reg;
      kp[gt*32 + nt*16 + r] = expf(accP[nt][reg] - xdk[reg]) * 0.17677669529663687f;
      qp[gt*32 + nt*16 + r] = expf(accQ[nt][reg] - xdq[reg]) * 0.17677669529663687f;
    }
  }
}

// ---------------- R1: partial kptv/ksum over 112-token segments ------------
__global__ void k_red(const bf16* __restrict__ v, const float* __restrict__ kp,
                      float* __restrict__ kptvP, float* __restrict__ ksumP){
  __shared__ float vS[16*64];
  __shared__ float kpS[16*32];
  int tid = threadIdx.x;
  int s = blockIdx.x, b = blockIdx.y;
  int tbase = b*TT + s*TSEG;
  float acc[8];
  #pragma unroll
  for (int p=0;p<8;p++) acc[p]=0.f;
  float ks = 0.f;
  int m  = tid & 31;
  int e0 = tid >> 5;
  for (int c=0;c<7;c++){
    __syncthreads();
    for (int idx=tid; idx<1024; idx+=256)
      vS[idx] = b2f(v[(size_t)(tbase + c*16 + (idx>>6))*64 + (idx&63)]);
    for (int idx=tid; idx<512; idx+=256)
      kpS[idx] = kp[(size_t)(tbase + c*16 + (idx>>5))*32 + (idx&31)];
    __syncthreads();
    #pragma unroll 4
    for (int t=0;t<16;t++){
      float kv = kpS[t*32 + m];
      #pragma unroll
      for (int p=0;p<8;p++)
        acc[p] = fmaf(vS[t*64 + e0 + 8*p], kv, acc[p]);
      if (tid < 32) ks += kpS[t*32 + tid];
    }
  }
  int ob = (b*SEG + s);
  #pragma unroll
  for (int p=0;p<8;p++) kptvP[ob*2048 + tid + 256*p] = acc[p];
  if (tid<32) ksumP[ob*32 + tid] = ks;
}

// ---------------- R2: final reduce (parallel: 8x32 blocks) -----------------
__global__ void k_red2(const float* __restrict__ kptvP, const float* __restrict__ ksumP,
                       float* __restrict__ kptvF, float* __restrict__ ksumF){
  int b = blockIdx.y, tid = threadIdx.x;
  int idx = blockIdx.x*256 + tid;
  float s = 0.f;
  #pragma unroll
  for (int g=0; g<SEG; ++g) s += kptvP[(b*SEG+g)*2048 + idx];
  kptvF[b*2048+idx] = s;
  if (blockIdx.x == 0 && tid < 32){
    float t = 0.f;
    #pragma unroll
    for (int g=0; g<SEG; ++g) t += ksumP[(b*SEG+g)*32 + tid];
    ksumF[b*32+tid] = t;
  }
}

// ---------------- B (MFMA): attn + proj + LN2 + MLP, 64 tokens/block -------
__global__ __launch_bounds__(256,2) void k_b(
    const float* __restrict__ qp, const bf16* __restrict__ v,
    const float* __restrict__ kptvF, const float* __restrict__ ksumF,
    const float* __restrict__ wprojF, const float* __restrict__ bprojF,
    const float* __restrict__ g2F, const float* __restrict__ be2F,
    const float* __restrict__ wm1F, const float* __restrict__ bm1F,
    const float* __restrict__ wm2F, const float* __restrict__ bm2F,
    const int* __restrict__ flagp, void* __restrict__ outp)
{
  __shared__ __align__(16) bf16 qpS[64*40];
  __shared__ __align__(16) bf16 kvS[64*40];
  __shared__ __align__(16) bf16 w0S[64*72];
  __shared__ __align__(16) bf16 w1S[64*72];
  __shared__ __align__(16) bf16 w2S[64*72];
  __shared__ __align__(16) bf16 vS[64*72];
  __shared__ __align__(16) bf16 stA[64*72];
  __shared__ __align__(16) bf16 stB[64*72];
  __shared__ float ksS[32];
  __shared__ float DS[64];
  __shared__ float bpS[64], b1S[64], b2S[64], gS[64], btS[64];

  int flag = *flagp;
  int tid = threadIdx.x;
  int b = blockIdx.y;
  int gt0 = b*TT + blockIdx.x*64;

  for (int i=tid; i<512; i+=256){
    int t = i>>3, q = i&7;
    float4 f = ((const float4*)qp)[(size_t)(gt0+t)*8 + q];
    union { bf16 h[4]; uint2 u; } cv;
    cv.h[0]=f2b(f.x); cv.h[1]=f2b(f.y); cv.h[2]=f2b(f.z); cv.h[3]=f2b(f.w);
    *((uint2*)&qpS[t*40 + q*4]) = cv.u;
  }
  for (int i=tid; i<512; i+=256){
    int e = i>>3, q = i&7;
    float4 f = ((const float4*)(kptvF + b*2048))[i];
    union { bf16 h[4]; uint2 u; } cv;
    cv.h[0]=f2b(f.x); cv.h[1]=f2b(f.y); cv.h[2]=f2b(f.z); cv.h[3]=f2b(f.w);
    *((uint2*)&kvS[e*40 + q*4]) = cv.u;
  }
  for (int i=tid; i<512; i+=256){
    int t = i>>3, q = i&7;
    uint4 u = ((const uint4*)(v + (size_t)gt0*64))[i];
    *((uint4*)&vS[t*72 + q*8]) = u;
  }
  {
    const float* Wsrc[3] = {wprojF, wm1F, wm2F};
    bf16* Wdst[3] = {w0S, w1S, w2S};
    for (int w=0; w<3; ++w)
      for (int i=tid; i<1024; i+=256){
        int e = i>>4, q = i&15;
        float4 f = ((const float4*)Wsrc[w])[i];
        union { bf16 h[4]; uint2 u; } cv;
        cv.h[0]=f2b(f.x); cv.h[1]=f2b(f.y); cv.h[2]=f2b(f.z); cv.h[3]=f2b(f.w);
        *((uint2*)&Wdst[w][e*72 + q*4]) = cv.u;
      }
  }
  if (tid<32) ksS[tid] = ksumF[b*32+tid];
  if (tid<64){
    bpS[tid]=bprojF[tid]; b1S[tid]=bm1F[tid]; b2S[tid]=bm2F[tid];
    gS[tid]=g2F[tid]; btS[tid]=be2F[tid];
  }
  __syncthreads();   // S1

  int tw = tid>>6, lane = tid&63, quad = lane>>4, r = lane&15;
  int tRow = tw*16 + quad*4;
  f4v zero = {0.f,0.f,0.f,0.f};

  if (tid < 64){
    float s = 0.f;
    #pragma unroll
    for (int m=0; m<32; ++m) s = fmaf(b2f(qpS[tid*40+m]), ksS[m], s);
    DS[tid] = s;
  }

  f4v accA[4];
  {
    s8v aq = *((const s8v*)&qpS[(tw*16+r)*40 + quad*8]);
    #pragma unroll
    for (int nt=0; nt<4; ++nt){
      s8v bk = *((const s8v*)&kvS[(nt*16+r)*40 + quad*8]);
      accA[nt] = __builtin_amdgcn_mfma_f32_16x16x32_bf16(aq, bk, zero, 0,0,0);
    }
  }
  __syncthreads();   // S2

  {
    float Dinv[4];
    #pragma unroll
    for (int reg=0; reg<4; ++reg) Dinv[reg] = 1.f/(DS[tRow+reg] + 1e-8f);
    #pragma unroll
    for (int nt=0; nt<4; ++nt)
      #pragma unroll
      for (int reg=0; reg<4; ++reg)
        stA[(tRow+reg)*72 + nt*16 + r] = f2b(accA[nt][reg]*Dinv[reg]);
  }
  __syncthreads();   // S3

  f4v accY[4] = {zero, zero, zero, zero};
  #pragma unroll
  for (int kh=0; kh<2; ++kh){
    s8v ay = *((const s8v*)&stA[(tw*16+r)*72 + kh*32 + quad*8]);
    #pragma unroll
    for (int nt=0; nt<4; ++nt){
      s8v bw = *((const s8v*)&w0S[(nt*16+r)*72 + kh*32 + quad*8]);
      accY[nt] = __builtin_amdgcn_mfma_f32_16x16x32_bf16(ay, bw, accY[nt], 0,0,0);
    }
  }
  float y[4][4];
  #pragma unroll
  for (int nt=0; nt<4; ++nt){
    int e = nt*16 + r;
    float bp = bpS[e];
    #pragma unroll
    for (int reg=0; reg<4; ++reg)
      y[nt][reg] = accY[nt][reg] + b2f(vS[(tRow+reg)*72 + e]) + bp;
  }

  float mu[4], rs[4];
  #pragma unroll
  for (int reg=0; reg<4; ++reg){
    float s = y[0][reg]+y[1][reg]+y[2][reg]+y[3][reg];
    #pragma unroll
    for (int off=1; off<16; off<<=1) s += __shfl_xor(s, off);
    mu[reg] = s * (1.f/64.f);
  }
  #pragma unroll
  for (int reg=0; reg<4; ++reg){
    float d2 = 0.f;
    #pragma unroll
    for (int nt=0; nt<4; ++nt){ float d = y[nt][reg]-mu[reg]; d2 = fmaf(d,d,d2); }
    #pragma unroll
    for (int off=1; off<16; off<<=1) d2 += __shfl_xor(d2, off);
    rs[reg] = rsqrtf(d2*(1.f/64.f) + 1e-5f);
  }
  #pragma unroll
  for (int nt=0; nt<4; ++nt){
    int e = nt*16 + r;
    float g = gS[e], be = btS[e];
    #pragma unroll
    for (int reg=0; reg<4; ++reg)
      stB[(tRow+reg)*72 + e] = f2b((y[nt][reg]-mu[reg])*rs[reg]*g + be);
  }
  __syncthreads();   // S4

  f4v accH[4] = {zero, zero, zero, zero};
  #pragma unroll
  for (int kh=0; kh<2; ++kh){
    s8v ah = *((const s8v*)&stB[(tw*16+r)*72 + kh*32 + quad*8]);
    #pragma unroll
    for (int nt=0; nt<4; ++nt){
      s8v bw = *((const s8v*)&w1S[(nt*16+r)*72 + kh*32 + quad*8]);
      accH[nt] = __builtin_amdgcn_mfma_f32_16x16x32_bf16(ah, bw, accH[nt], 0,0,0);
    }
  }
  #pragma unroll
  for (int nt=0; nt<4; ++nt){
    int e = nt*16 + r;
    float b1 = b1S[e];
    #pragma unroll
    for (int reg=0; reg<4; ++reg){
      float h = accH[nt][reg] + b1;
      h = 0.5f*h*(1.f + erff(h*0.70710678118654752f));
      stA[(tRow+reg)*72 + e] = f2b(h);
    }
  }
  __syncthreads();   // S5

  f4v accO[4] = {zero, zero, zero, zero};
  #pragma unroll
  for (int kh=0; kh<2; ++kh){
    s8v ao = *((const s8v*)&stA[(tw*16+r)*72 + kh*32 + quad*8]);
    #pragma unroll
    for (int nt=0; nt<4; ++nt){
      s8v bw = *((const s8v*)&w2S[(nt*16+r)*72 + kh*32 + quad*8]);
      accO[nt] = __builtin_amdgcn_mfma_f32_16x16x32_bf16(ao, bw, accO[nt], 0,0,0);
    }
  }
  if (flag){
    bf16* o = (bf16*)outp;
    #pragma unroll
    for (int nt=0; nt<4; ++nt){
      int e = nt*16 + r;
      float b2 = b2S[e];
      #pragma unroll
      for (int reg=0; reg<4; ++reg)
        o[(size_t)(gt0 + tRow + reg)*64 + e] = f2b(y[nt][reg] + accO[nt][reg] + b2);
    }
  } else {
    float* o = (float*)outp;
    #pragma unroll
    for (int nt=0; nt<4; ++nt){
      int e = nt*16 + r;
      float b2 = b2S[e];
      #pragma unroll
      for (int reg=0; reg<4; ++reg)
        o[(size_t)(gt0 + tRow + reg)*64 + e] = y[nt][reg] + accO[nt][reg] + b2;
    }
  }
}

// ---------------- launcher -------------------------------------------------
extern "C" void kernel_launch(void* const* d_in, const int* in_sizes, int n_in,
                              void* d_out, int out_size, void* d_ws, size_t ws_size,
                              hipStream_t stream){
  const void* x    = d_in[0];
  const void* wkqv = d_in[1];
  const void* bkqv = d_in[2];
  const void* wproj= d_in[3];
  const void* bproj= d_in[4];
  const void* g1   = d_in[5];
  const void* be1  = d_in[6];
  const void* g2   = d_in[7];
  const void* be2  = d_in[8];
  const void* wm1  = d_in[9];
  const void* bm1  = d_in[10];
  const void* wm2  = d_in[11];
  const void* bm2  = d_in[12];
  const void* Wrf  = d_in[13];

  char* ws = (char*)d_ws;
  int*   flagp = (int*)(ws + 0);
  bf16*  Bprep = (bf16*) (ws + 256);
  float* bkqvF = (float*)(ws + 61696);
  bf16*  WrfB  = (bf16*) (ws + 62464);
  float* wprojF= (float*)(ws + 66560);
  float* bprojF= (float*)(ws + 82944);
  float* g2F   = (float*)(ws + 83200);
  float* be2F  = (float*)(ws + 83456);
  float* wm1F  = (float*)(ws + 83712);
  float* bm1F  = (float*)(ws + 100096);
  float* wm2F  = (float*)(ws + 100352);
  float* bm2F  = (float*)(ws + 116736);
  float* g1F   = (float*)(ws + 116992);
  float* be1F  = (float*)(ws + 117760);
  bf16*  xn    = (bf16*) (ws + 118784);            // BT*160*2 = 32112640 B
  // alias into dead xn region (k_red runs after k_a2's last xn read):
  float* kptvP = (float*)(ws + 118784);            // 7340032 B
  float* ksumP = (float*)(ws + 7458816);           // 114688 B
  float* kptvF = (float*)(ws + 7573504);           // 262144 B
  float* ksumF = (float*)(ws + 7835648);           // 4096 B
  float* kp    = (float*)(ws + 32231424);          // 12845056 B
  float* qp    = (float*)(ws + 45076480);          // 12845056 B
  bf16*  v     = (bf16*) (ws + 57921536);          // 12845056 B -> end 70766592

  k_detect<<<1, 64, 0, stream>>>((const unsigned*)g1, flagp);
  k_cvt<<<180, 256, 0, stream>>>(wkqv, bkqv, Wrf, wproj, bproj, g2, be2,
      wm1, bm1, wm2, bm2, g1, be1, flagp,
      Bprep, bkqvF, WrfB, wprojF, bprojF, g2F, be2F, wm1F, bm1F, wm2F, bm2F, g1F, be1F);
  k_ln1<<<BT/4, 256, 0, stream>>>(x, g1F, be1F, flagp, xn);
  k_a2<<<BT/64, 256, 0, stream>>>(xn, Bprep, bkqvF, WrfB, kp, qp, v);
  k_red<<<dim3(SEG, BB), 256, 0, stream>>>(v, kp, kptvP, ksumP);
  k_red2<<<dim3(8, BB), 256, 0, stream>>>(kptvP, ksumP, kptvF, ksumF);
  k_b<<<dim3(TT/64, BB), 256, 0, stream>>>(qp, v, kptvF, ksumF,
      wprojF, bprojF, g2F, be2F, wm1F, bm1F, wm2F, bm2F, flagp, d_out);
}

// Round 7
// 220.685 us; speedup vs baseline: 4.5615x; 1.1046x over previous
//
#include <hip/hip_runtime.h>
#include <hip/hip_bf16.h>

#define BB 32
#define TT 3136
#define DD 147
#define EE 64
#define MM 32
#define BT (BB*TT)      // 100352

typedef __hip_bfloat16 bf16;
typedef __attribute__((ext_vector_type(8))) short s8v;
typedef __attribute__((ext_vector_type(4))) float f4v;

__device__ __forceinline__ float b2f(bf16 v){ return __bfloat162float(v); }
__device__ __forceinline__ bf16 f2b(float v){ return __float2bfloat16(v); }
__device__ __forceinline__ unsigned pack2(float a, float b){
  union { bf16 h[2]; unsigned u; } cv; cv.h[0]=f2b(a); cv.h[1]=f2b(b); return cv.u;
}

template<typename T>
__device__ __forceinline__ float cvt1(T v);
template<> __device__ __forceinline__ float cvt1<float>(float v){ return v; }
template<> __device__ __forceinline__ float cvt1<bf16>(bf16 v){ return __bfloat162float(v); }

// ---------------- detect: inputs bf16 (flag=1) or fp32 (flag=0) ------------
__global__ void k_detect(const unsigned* __restrict__ g1u, int* __restrict__ flagp){
  if (threadIdx.x == 0 && blockIdx.x == 0)
    *flagp = (g1u[0] == 0x3F803F80u) ? 1 : 0;
}

// ---------------- zero: kptvF/ksumF (ws is poisoned each call) -------------
__global__ void k_zero(float* __restrict__ kptvF, float* __restrict__ ksumF){
  int i = blockIdx.x*256 + threadIdx.x;
  if (i < 65536) kptvF[i] = 0.f;
  if (i < 1024)  ksumF[i] = 0.f;
}

// ---------------- cvt: weights -> canonical layouts in ws ------------------
template<typename T>
__device__ void cvt_body(int idx,
    const T* wkqv, const T* bkqv, const T* Wrf, const T* wproj, const T* bproj,
    const T* g2, const T* be2, const T* wm1, const T* bm1, const T* wm2,
    const T* bm2, const T* g1, const T* be1,
    bf16* Bprep, float* bkqvF, bf16* WrfB, float* wprojF, float* bprojF,
    float* g2F, float* be2F, float* wm1F, float* bm1F, float* wm2F,
    float* bm2F, float* g1F, float* be1F)
{
  if (idx < 30720){
    int n = idx/160, k = idx - n*160;
    Bprep[idx] = f2b(k < DD ? cvt1(wkqv[n*DD + k]) : 0.f);
    return;
  }
  idx -= 30720;
  if (idx < 192){ bkqvF[idx] = cvt1(bkqv[idx]); return; }
  idx -= 192;
  if (idx < 2048){ WrfB[idx] = f2b(cvt1(Wrf[idx])); return; }
  idx -= 2048;
  if (idx < 4096){ wprojF[idx] = cvt1(wproj[idx]); return; }
  idx -= 4096;
  if (idx < 64){ bprojF[idx] = cvt1(bproj[idx]); return; }
  idx -= 64;
  if (idx < 64){ g2F[idx] = cvt1(g2[idx]); return; }
  idx -= 64;
  if (idx < 64){ be2F[idx] = cvt1(be2[idx]); return; }
  idx -= 64;
  if (idx < 4096){ wm1F[idx] = cvt1(wm1[idx]); return; }
  idx -= 4096;
  if (idx < 64){ bm1F[idx] = cvt1(bm1[idx]); return; }
  idx -= 64;
  if (idx < 4096){ wm2F[idx] = cvt1(wm2[idx]); return; }
  idx -= 4096;
  if (idx < 64){ bm2F[idx] = cvt1(bm2[idx]); return; }
  idx -= 64;
  if (idx < DD){ g1F[idx] = cvt1(g1[idx]); return; }
  idx -= DD;
  if (idx < DD){ be1F[idx] = cvt1(be1[idx]); return; }
}

__global__ void k_cvt(const void* wkqv, const void* bkqv, const void* Wrf,
    const void* wproj, const void* bproj, const void* g2, const void* be2,
    const void* wm1, const void* bm1, const void* wm2, const void* bm2,
    const void* g1, const void* be1, const int* __restrict__ flagp,
    bf16* Bprep, float* bkqvF, bf16* WrfB, float* wprojF, float* bprojF,
    float* g2F, float* be2F, float* wm1F, float* bm1F, float* wm2F,
    float* bm2F, float* g1F, float* be1F)
{
  int idx = blockIdx.x*256 + threadIdx.x;
  if (*flagp)
    cvt_body<bf16>(idx, (const bf16*)wkqv, (const bf16*)bkqv, (const bf16*)Wrf,
      (const bf16*)wproj, (const bf16*)bproj, (const bf16*)g2, (const bf16*)be2,
      (const bf16*)wm1, (const bf16*)bm1, (const bf16*)wm2, (const bf16*)bm2,
      (const bf16*)g1, (const bf16*)be1,
      Bprep, bkqvF, WrfB, wprojF, bprojF, g2F, be2F, wm1F, bm1F, wm2F, bm2F, g1F, be1F);
  else
    cvt_body<float>(idx, (const float*)wkqv, (const float*)bkqv, (const float*)Wrf,
      (const float*)wproj, (const float*)bproj, (const float*)g2, (const float*)be2,
      (const float*)wm1, (const float*)bm1, (const float*)wm2, (const float*)bm2,
      (const float*)g1, (const float*)be1,
      Bprep, bkqvF, WrfB, wprojF, bprojF, g2F, be2F, wm1F, bm1F, wm2F, bm2F, g1F, be1F);
}

// ---------------- LN1: wave per token, output stride 160 (zero tail) -------
template<typename T>
__device__ void ln1_body(const T* __restrict__ x, const float* __restrict__ g1F,
                         const float* __restrict__ be1F, bf16* __restrict__ xn){
  int lane = threadIdx.x & 63;
  int t = blockIdx.x*4 + (threadIdx.x>>6);
  size_t base = (size_t)t*DD;
  float v0 = cvt1(x[base+lane]);
  float v1 = cvt1(x[base+64+lane]);
  float v2 = (lane < DD-128) ? cvt1(x[base+128+lane]) : 0.f;
  float s = v0+v1+v2, s2 = v0*v0+v1*v1+v2*v2;
  #pragma unroll
  for (int off=32; off; off>>=1){ s += __shfl_xor(s,off); s2 += __shfl_xor(s2,off); }
  float mu  = s * (1.f/147.f);
  float var = s2 * (1.f/147.f) - mu*mu;
  float r = rsqrtf(var + 1e-5f);
  bf16* xo = xn + (size_t)t*160;
  xo[lane]    = f2b((v0-mu)*r*g1F[lane]    + be1F[lane]);
  xo[64+lane] = f2b((v1-mu)*r*g1F[64+lane] + be1F[64+lane]);
  if (lane < 32)
    xo[128+lane] = (lane < DD-128)
      ? f2b((v2-mu)*r*g1F[128+lane] + be1F[128+lane]) : f2b(0.f);
}

__global__ void k_ln1(const void* __restrict__ x, const float* __restrict__ g1F,
                      const float* __restrict__ be1F, const int* __restrict__ flagp,
                      bf16* __restrict__ xn){
  if (*flagp) ln1_body<bf16>((const bf16*)x, g1F, be1F, xn);
  else        ln1_body<float>((const float*)x, g1F, be1F, xn);
}

// ---------------- A2 (MFMA): kqv GEMM + prm_exp + fused kptv/ksum ----------
// C/D: col=lane&15, row=quad*4+reg.  A: A[m=lane&15][k=quad*8+j].
// B: B[k=quad*8+j][n=lane&15].
// Block = 64 tokens (one batch; 49 blocks/batch); wave tw owns tokens tw*16..+15.
__global__ __launch_bounds__(256) void k_a2(
    const bf16* __restrict__ xn, const bf16* __restrict__ Bprep,
    const float* __restrict__ bkqvF, const bf16* __restrict__ WrfB,
    bf16* __restrict__ qp, bf16* __restrict__ v,
    float* __restrict__ kptvF, float* __restrict__ ksumF)
{
  // region0 (21504 B): aS [64][168] bf16  -- after main GEMM, reused as
  //                    vT [64][72] bf16 (9216 B) + kpT [32][72] bf16 (4608 B)
  // region1 (17408 B): kqS [64][136] bf16
  __shared__ __align__(16) char smem[38912];
  bf16* aS  = (bf16*)smem;
  bf16* vT  = (bf16*)smem;
  bf16* kpT = (bf16*)(smem + 9216);
  bf16* kqS = (bf16*)(smem + 21504);

  int tid = threadIdx.x;
  size_t t0 = (size_t)blockIdx.x*64;
  int b = blockIdx.x / 49;

  // stage A tile: 64 rows x 160 bf16 = 1280 uint4
  const uint4* xg = (const uint4*)(xn + t0*160);
  for (int i=tid; i<1280; i+=256){
    int row = i/20, ch = i - row*20;
    uint4 u = xg[i];
    *((uint4*)&aS[row*168 + ch*8]) = u;
  }
  __syncthreads();   // S1

  int tw = tid>>6, lane = tid&63, quad = lane>>4, r = lane&15;
  int tRow = tw*16 + quad*4;
  f4v zero = {0.f,0.f,0.f,0.f};

  // ---- main GEMM: kqv[t][n] = sum_k xn[t][k] * wkqv[n][k], K=160 ----
  f4v acc[12];
  #pragma unroll
  for (int nt=0; nt<12; ++nt) acc[nt] = zero;
  const bf16* aBase = &aS[(tw*16+r)*168 + quad*8];
  const bf16* bBase = &Bprep[r*160 + quad*8];
  #pragma unroll 1
  for (int ks=0; ks<5; ++ks){
    s8v a = *((const s8v*)(aBase + ks*32));
    #pragma unroll
    for (int nt=0; nt<12; ++nt){
      s8v bw = *((const s8v*)(bBase + nt*16*160 + ks*32));
      acc[nt] = __builtin_amdgcn_mfma_f32_16x16x32_bf16(a, bw, acc[nt], 0,0,0);
    }
  }

  float bias[12];
  #pragma unroll
  for (int nt=0; nt<12; ++nt) bias[nt] = bkqvF[nt*16 + r];

  // v values (channels 128..191): keep in regs + write global
  float vv[4][4];
  #pragma unroll
  for (int nt=8; nt<12; ++nt){
    #pragma unroll
    for (int reg=0; reg<4; ++reg){
      vv[nt-8][reg] = acc[nt][reg] + bias[nt];
      v[(t0 + tRow + reg)*64 + (nt-8)*16 + r] = f2b(vv[nt-8][reg]);
    }
  }

  // biased k,q
  float kq[8][4];
  #pragma unroll
  for (int nt=0; nt<8; ++nt)
    #pragma unroll
    for (int reg=0; reg<4; ++reg)
      kq[nt][reg] = acc[nt][reg] + bias[nt];

  // kq -> LDS [t][0..127] stride 136 (each wave touches only its own strip)
  #pragma unroll
  for (int nt=0; nt<8; ++nt)
    #pragma unroll
    for (int reg=0; reg<4; ++reg)
      kqS[(tRow+reg)*136 + nt*16 + r] = f2b(kq[nt][reg]);

  // xd = 0.5*||.||^2 per token row
  float xdk[4], xdq[4];
  #pragma unroll
  for (int reg=0; reg<4; ++reg){
    float sk = 0.f, sq = 0.f;
    #pragma unroll
    for (int nt=0; nt<4; ++nt){
      sk = fmaf(kq[nt][reg],   kq[nt][reg],   sk);
      sq = fmaf(kq[nt+4][reg], kq[nt+4][reg], sq);
    }
    #pragma unroll
    for (int off=1; off<16; off<<=1){
      sk += __shfl_xor(sk, off);
      sq += __shfl_xor(sq, off);
    }
    xdk[reg] = 0.5f*sk;
    xdq[reg] = 0.5f*sq;
  }
  __syncthreads();   // S2: aS reads done everywhere; kqS visible

  // ---- prm_exp GEMM: pre[t][m] = sum_e kq[t][e] * Wrf[m][e], K=64 ----
  f4v accP[2] = {zero, zero}, accQ[2] = {zero, zero};
  #pragma unroll
  for (int ks=0; ks<2; ++ks){
    s8v ak = *((const s8v*)&kqS[(tw*16+r)*136 + ks*32 + quad*8]);
    s8v aq = *((const s8v*)&kqS[(tw*16+r)*136 + 64 + ks*32 + quad*8]);
    #pragma unroll
    for (int nt=0; nt<2; ++nt){
      s8v wf = *((const s8v*)&WrfB[(nt*16+r)*64 + ks*32 + quad*8]);
      accP[nt] = __builtin_amdgcn_mfma_f32_16x16x32_bf16(ak, wf, accP[nt], 0,0,0);
      accQ[nt] = __builtin_amdgcn_mfma_f32_16x16x32_bf16(aq, wf, accQ[nt], 0,0,0);
    }
  }
  float kpv[2][4];
  #pragma unroll
  for (int nt=0; nt<2; ++nt){
    #pragma unroll
    for (int reg=0; reg<4; ++reg){
      size_t gt = t0 + tRow + reg;
      kpv[nt][reg] = expf(accP[nt][reg] - xdk[reg]) * 0.17677669529663687f;
      qp[gt*32 + nt*16 + r] = f2b(expf(accQ[nt][reg] - xdq[reg]) * 0.17677669529663687f);
    }
  }

  // vT[e][t] and kpT[m][t] into (dead) aS region, packed 2-at-a-time in t
  #pragma unroll
  for (int nt=0; nt<4; ++nt){
    *((unsigned*)&vT[(nt*16+r)*72 + tRow])     = pack2(vv[nt][0], vv[nt][1]);
    *((unsigned*)&vT[(nt*16+r)*72 + tRow + 2]) = pack2(vv[nt][2], vv[nt][3]);
  }
  #pragma unroll
  for (int nt=0; nt<2; ++nt){
    *((unsigned*)&kpT[(nt*16+r)*72 + tRow])     = pack2(kpv[nt][0], kpv[nt][1]);
    *((unsigned*)&kpT[(nt*16+r)*72 + tRow + 2]) = pack2(kpv[nt][2], kpv[nt][3]);
  }

  // ksum partial: sum over this wave's 16 tokens (4 regs + quad reduce)
  float ks0 = kpv[0][0]+kpv[0][1]+kpv[0][2]+kpv[0][3];
  float ks1 = kpv[1][0]+kpv[1][1]+kpv[1][2]+kpv[1][3];
  ks0 += __shfl_xor(ks0, 16); ks0 += __shfl_xor(ks0, 32);
  ks1 += __shfl_xor(ks1, 16); ks1 += __shfl_xor(ks1, 32);
  if (lane < 16){
    atomicAdd(&ksumF[b*32 + r],      ks0);
    atomicAdd(&ksumF[b*32 + 16 + r], ks1);
  }
  __syncthreads();   // S3: vT/kpT visible

  // ---- kptv partial: C[e][m] = sum_t v[t][e]*kp[t][m], K=64 ----
  f4v accKV[2] = {zero, zero};
  #pragma unroll
  for (int kh=0; kh<2; ++kh){
    s8v av = *((const s8v*)&vT[(tw*16+r)*72 + kh*32 + quad*8]);
    #pragma unroll
    for (int nt=0; nt<2; ++nt){
      s8v bk = *((const s8v*)&kpT[(nt*16+r)*72 + kh*32 + quad*8]);
      accKV[nt] = __builtin_amdgcn_mfma_f32_16x16x32_bf16(av, bk, accKV[nt], 0,0,0);
    }
  }
  float* dst = kptvF + b*2048;
  #pragma unroll
  for (int nt=0; nt<2; ++nt)
    #pragma unroll
    for (int reg=0; reg<4; ++reg)
      atomicAdd(&dst[(tw*16 + quad*4 + reg)*32 + nt*16 + r], accKV[nt][reg]);
}

// ---------------- B (MFMA): attn + proj + LN2 + MLP, 64 tokens/block -------
__global__ __launch_bounds__(256,2) void k_b(
    const bf16* __restrict__ qp, const bf16* __restrict__ v,
    const float* __restrict__ kptvF, const float* __restrict__ ksumF,
    const float* __restrict__ wprojF, const float* __restrict__ bprojF,
    const float* __restrict__ g2F, const float* __restrict__ be2F,
    const float* __restrict__ wm1F, const float* __restrict__ bm1F,
    const float* __restrict__ wm2F, const float* __restrict__ bm2F,
    const int* __restrict__ flagp, void* __restrict__ outp)
{
  __shared__ __align__(16) bf16 qpS[64*40];
  __shared__ __align__(16) bf16 kvS[64*40];
  __shared__ __align__(16) bf16 w0S[64*72];
  __shared__ __align__(16) bf16 w1S[64*72];
  __shared__ __align__(16) bf16 w2S[64*72];
  __shared__ __align__(16) bf16 vS[64*72];
  __shared__ __align__(16) bf16 stA[64*72];
  __shared__ __align__(16) bf16 stB[64*72];
  __shared__ float ksS[32];
  __shared__ float DS[64];
  __shared__ float bpS[64], b1S[64], b2S[64], gS[64], btS[64];

  int flag = *flagp;
  int tid = threadIdx.x;
  int b = blockIdx.y;
  int gt0 = b*TT + blockIdx.x*64;

  // qp bf16 [64][32] -> LDS stride 40 (4 uint4 per row)
  {
    int t = tid>>2, q = tid&3;
    uint4 u = ((const uint4*)(qp + (size_t)gt0*32))[tid];
    *((uint4*)&qpS[t*40 + q*8]) = u;
  }
  for (int i=tid; i<512; i+=256){
    int e = i>>3, q = i&7;
    float4 f = ((const float4*)(kptvF + b*2048))[i];
    union { bf16 h[4]; uint2 u; } cv;
    cv.h[0]=f2b(f.x); cv.h[1]=f2b(f.y); cv.h[2]=f2b(f.z); cv.h[3]=f2b(f.w);
    *((uint2*)&kvS[e*40 + q*4]) = cv.u;
  }
  for (int i=tid; i<512; i+=256){
    int t = i>>3, q = i&7;
    uint4 u = ((const uint4*)(v + (size_t)gt0*64))[i];
    *((uint4*)&vS[t*72 + q*8]) = u;
  }
  {
    const float* Wsrc[3] = {wprojF, wm1F, wm2F};
    bf16* Wdst[3] = {w0S, w1S, w2S};
    for (int w=0; w<3; ++w)
      for (int i=tid; i<1024; i+=256){
        int e = i>>4, q = i&15;
        float4 f = ((const float4*)Wsrc[w])[i];
        union { bf16 h[4]; uint2 u; } cv;
        cv.h[0]=f2b(f.x); cv.h[1]=f2b(f.y); cv.h[2]=f2b(f.z); cv.h[3]=f2b(f.w);
        *((uint2*)&Wdst[w][e*72 + q*4]) = cv.u;
      }
  }
  if (tid<32) ksS[tid] = ksumF[b*32+tid];
  if (tid<64){
    bpS[tid]=bprojF[tid]; b1S[tid]=bm1F[tid]; b2S[tid]=bm2F[tid];
    gS[tid]=g2F[tid]; btS[tid]=be2F[tid];
  }
  __syncthreads();   // S1

  int tw = tid>>6, lane = tid&63, quad = lane>>4, r = lane&15;
  int tRow = tw*16 + quad*4;
  f4v zero = {0.f,0.f,0.f,0.f};

  if (tid < 64){
    float s = 0.f;
    #pragma unroll
    for (int m=0; m<32; ++m) s = fmaf(b2f(qpS[tid*40+m]), ksS[m], s);
    DS[tid] = s;
  }

  f4v accA[4];
  {
    s8v aq = *((const s8v*)&qpS[(tw*16+r)*40 + quad*8]);
    #pragma unroll
    for (int nt=0; nt<4; ++nt){
      s8v bk = *((const s8v*)&kvS[(nt*16+r)*40 + quad*8]);
      accA[nt] = __builtin_amdgcn_mfma_f32_16x16x32_bf16(aq, bk, zero, 0,0,0);
    }
  }
  __syncthreads();   // S2

  {
    float Dinv[4];
    #pragma unroll
    for (int reg=0; reg<4; ++reg) Dinv[reg] = 1.f/(DS[tRow+reg] + 1e-8f);
    #pragma unroll
    for (int nt=0; nt<4; ++nt)
      #pragma unroll
      for (int reg=0; reg<4; ++reg)
        stA[(tRow+reg)*72 + nt*16 + r] = f2b(accA[nt][reg]*Dinv[reg]);
  }
  __syncthreads();   // S3

  f4v accY[4] = {zero, zero, zero, zero};
  #pragma unroll
  for (int kh=0; kh<2; ++kh){
    s8v ay = *((const s8v*)&stA[(tw*16+r)*72 + kh*32 + quad*8]);
    #pragma unroll
    for (int nt=0; nt<4; ++nt){
      s8v bw = *((const s8v*)&w0S[(nt*16+r)*72 + kh*32 + quad*8]);
      accY[nt] = __builtin_amdgcn_mfma_f32_16x16x32_bf16(ay, bw, accY[nt], 0,0,0);
    }
  }
  float y[4][4];
  #pragma unroll
  for (int nt=0; nt<4; ++nt){
    int e = nt*16 + r;
    float bp = bpS[e];
    #pragma unroll
    for (int reg=0; reg<4; ++reg)
      y[nt][reg] = accY[nt][reg] + b2f(vS[(tRow+reg)*72 + e]) + bp;
  }

  float mu[4], rs[4];
  #pragma unroll
  for (int reg=0; reg<4; ++reg){
    float s = y[0][reg]+y[1][reg]+y[2][reg]+y[3][reg];
    #pragma unroll
    for (int off=1; off<16; off<<=1) s += __shfl_xor(s, off);
    mu[reg] = s * (1.f/64.f);
  }
  #pragma unroll
  for (int reg=0; reg<4; ++reg){
    float d2 = 0.f;
    #pragma unroll
    for (int nt=0; nt<4; ++nt){ float d = y[nt][reg]-mu[reg]; d2 = fmaf(d,d,d2); }
    #pragma unroll
    for (int off=1; off<16; off<<=1) d2 += __shfl_xor(d2, off);
    rs[reg] = rsqrtf(d2*(1.f/64.f) + 1e-5f);
  }
  #pragma unroll
  for (int nt=0; nt<4; ++nt){
    int e = nt*16 + r;
    float g = gS[e], be = btS[e];
    #pragma unroll
    for (int reg=0; reg<4; ++reg)
      stB[(tRow+reg)*72 + e] = f2b((y[nt][reg]-mu[reg])*rs[reg]*g + be);
  }
  __syncthreads();   // S4

  f4v accH[4] = {zero, zero, zero, zero};
  #pragma unroll
  for (int kh=0; kh<2; ++kh){
    s8v ah = *((const s8v*)&stB[(tw*16+r)*72 + kh*32 + quad*8]);
    #pragma unroll
    for (int nt=0; nt<4; ++nt){
      s8v bw = *((const s8v*)&w1S[(nt*16+r)*72 + kh*32 + quad*8]);
      accH[nt] = __builtin_amdgcn_mfma_f32_16x16x32_bf16(ah, bw, accH[nt], 0,0,0);
    }
  }
  #pragma unroll
  for (int nt=0; nt<4; ++nt){
    int e = nt*16 + r;
    float b1 = b1S[e];
    #pragma unroll
    for (int reg=0; reg<4; ++reg){
      float h = accH[nt][reg] + b1;
      h = 0.5f*h*(1.f + erff(h*0.70710678118654752f));
      stA[(tRow+reg)*72 + e] = f2b(h);
    }
  }
  __syncthreads();   // S5

  f4v accO[4] = {zero, zero, zero, zero};
  #pragma unroll
  for (int kh=0; kh<2; ++kh){
    s8v ao = *((const s8v*)&stA[(tw*16+r)*72 + kh*32 + quad*8]);
    #pragma unroll
    for (int nt=0; nt<4; ++nt){
      s8v bw = *((const s8v*)&w2S[(nt*16+r)*72 + kh*32 + quad*8]);
      accO[nt] = __builtin_amdgcn_mfma_f32_16x16x32_bf16(ao, bw, accO[nt], 0,0,0);
    }
  }
  if (flag){
    bf16* o = (bf16*)outp;
    #pragma unroll
    for (int nt=0; nt<4; ++nt){
      int e = nt*16 + r;
      float b2 = b2S[e];
      #pragma unroll
      for (int reg=0; reg<4; ++reg)
        o[(size_t)(gt0 + tRow + reg)*64 + e] = f2b(y[nt][reg] + accO[nt][reg] + b2);
    }
  } else {
    float* o = (float*)outp;
    #pragma unroll
    for (int nt=0; nt<4; ++nt){
      int e = nt*16 + r;
      float b2 = b2S[e];
      #pragma unroll
      for (int reg=0; reg<4; ++reg)
        o[(size_t)(gt0 + tRow + reg)*64 + e] = y[nt][reg] + accO[nt][reg] + b2;
    }
  }
}

// ---------------- launcher -------------------------------------------------
extern "C" void kernel_launch(void* const* d_in, const int* in_sizes, int n_in,
                              void* d_out, int out_size, void* d_ws, size_t ws_size,
                              hipStream_t stream){
  const void* x    = d_in[0];
  const void* wkqv = d_in[1];
  const void* bkqv = d_in[2];
  const void* wproj= d_in[3];
  const void* bproj= d_in[4];
  const void* g1   = d_in[5];
  const void* be1  = d_in[6];
  const void* g2   = d_in[7];
  const void* be2  = d_in[8];
  const void* wm1  = d_in[9];
  const void* bm1  = d_in[10];
  const void* wm2  = d_in[11];
  const void* bm2  = d_in[12];
  const void* Wrf  = d_in[13];

  char* ws = (char*)d_ws;
  int*   flagp = (int*)(ws + 0);
  bf16*  Bprep = (bf16*) (ws + 256);
  float* bkqvF = (float*)(ws + 61696);
  bf16*  WrfB  = (bf16*) (ws + 62464);
  float* wprojF= (float*)(ws + 66560);
  float* bprojF= (float*)(ws + 82944);
  float* g2F   = (float*)(ws + 83200);
  float* be2F  = (float*)(ws + 83456);
  float* wm1F  = (float*)(ws + 83712);
  float* bm1F  = (float*)(ws + 100096);
  float* wm2F  = (float*)(ws + 100352);
  float* bm2F  = (float*)(ws + 116736);
  float* g1F   = (float*)(ws + 116992);
  float* be1F  = (float*)(ws + 117760);
  bf16*  xn    = (bf16*) (ws + 118784);            // BT*160*2 = 32112640 B
  float* kptvF = (float*)(ws + 32231424);          // 262144 B
  float* ksumF = (float*)(ws + 32493568);          // 4096 B
  bf16*  qp    = (bf16*) (ws + 32497664);          // 6422528 B
  bf16*  v     = (bf16*) (ws + 38920192);          // 12845056 B -> end 51765248

  k_detect<<<1, 64, 0, stream>>>((const unsigned*)g1, flagp);
  k_cvt<<<180, 256, 0, stream>>>(wkqv, bkqv, Wrf, wproj, bproj, g2, be2,
      wm1, bm1, wm2, bm2, g1, be1, flagp,
      Bprep, bkqvF, WrfB, wprojF, bprojF, g2F, be2F, wm1F, bm1F, wm2F, bm2F, g1F, be1F);
  k_zero<<<256, 256, 0, stream>>>(kptvF, ksumF);
  k_ln1<<<BT/4, 256, 0, stream>>>(x, g1F, be1F, flagp, xn);
  k_a2<<<BT/64, 256, 0, stream>>>(xn, Bprep, bkqvF, WrfB, qp, v, kptvF, ksumF);
  k_b<<<dim3(TT/64, BB), 256, 0, stream>>>(qp, v, kptvF, ksumF,
      wprojF, bprojF, g2F, be2F, wm1F, bm1F, wm2F, bm2F, flagp, d_out);
}